// Round 1
// baseline (8602.888 us; speedup 1.0000x reference)
//
#include <hip/hip_runtime.h>
#include <hip/hip_bf16.h>

typedef __attribute__((ext_vector_type(8))) unsigned short ushort8;

__device__ __forceinline__ float bf2f(unsigned short u){
  union { unsigned int i; float f; } x; x.i = ((unsigned int)u) << 16; return x.f;
}
__device__ __forceinline__ unsigned short f2bf(float f){
  __hip_bfloat16 h = __float2bfloat16(f);
  return *reinterpret_cast<unsigned short*>(&h);
}

// ---- CSR row_ptr via binary search over sorted row[] ----
__global__ void rowptr_k(const int* __restrict__ row, int nnz, int* __restrict__ rp, int V){
  int v = blockIdx.x*blockDim.x + threadIdx.x;
  if (v > V) return;
  int lo = 0, hi = nnz;
  while (lo < hi){ int m = (lo+hi)>>1; if (row[m] < v) lo = m+1; else hi = m; }
  rp[v] = lo;
}

// ---- zero small buffer ----
__global__ void zero_k(float* __restrict__ p, int n){
  int i = blockIdx.x*blockDim.x + threadIdx.x;
  if (i < n) p[i] = 0.f;
}

// ---- encoder linear 1 (3 -> 64) + bias, out bf16 ----
__global__ void lin1_k(const float* __restrict__ x, const float* __restrict__ W,
                       const float* __restrict__ b, unsigned short* __restrict__ out, int R){
  __shared__ float sW[192];
  __shared__ float sB[64];
  int tid = threadIdx.x;
  if (tid < 192) sW[tid] = W[tid];
  if (tid < 64)  sB[tid] = b[tid];
  __syncthreads();
  int idx = blockIdx.x*256 + tid;
  if (idx >= R*64) return;
  int c = idx & 63, r = idx >> 6;
  const float* xr = x + (size_t)r*3;
  float acc = sB[c] + xr[0]*sW[c*3+0] + xr[1]*sW[c*3+1] + xr[2]*sW[c*3+2];
  out[idx] = f2bf(acc);
}

// ---- SPMM (normalized adjacency) + ReLU, bf16 in/out, fp32 accum ----
template<int C>
__global__ void spmm_relu_k(const unsigned short* __restrict__ in, unsigned short* __restrict__ out,
                            const int* __restrict__ rp, const int* __restrict__ colx,
                            const float* __restrict__ vals, int Bn, int V){
  int idx = blockIdx.x*256 + threadIdx.x;
  if (idx >= Bn*V*C) return;
  int c = idx % C; int v = (idx / C) % V; int b = idx / (C*V);
  const unsigned short* base = in + (size_t)b*V*C;
  float acc = 0.f;
  int e1 = rp[v+1];
  for (int e = rp[v]; e < e1; ++e){
    acc += vals[e] * bf2f(base[(size_t)colx[e]*C + c]);
  }
  out[idx] = f2bf(acc > 0.f ? acc : 0.f);
}

// ---- tiled dense linear: [R,K] bf16 @ W[N,K] fp32 (+bias, opt ReLU) -> [R,N] bf16 ----
// 64 rows per block, weights+inputs staged in LDS as bf16 (rows padded +8 -> 2-way
// bank conflicts only, free), 4xTN register tile per thread, fp32 FMA accumulate.
template<int K, int N, bool RELU>
__global__ __launch_bounds__(256) void lin_tiled_k(const unsigned short* __restrict__ in,
    const float* __restrict__ W, const float* __restrict__ bias,
    unsigned short* __restrict__ out, int R){
  constexpr int KP = K + 8;
  constexpr int TN = N / 16;
  __shared__ unsigned short sIn[64][KP];
  __shared__ unsigned short sW[N][KP];
  __shared__ float sB[N];
  int tid = threadIdx.x;
  for (int i = tid; i < N*K; i += 256){ int n = i / K, k = i % K; sW[n][k] = f2bf(W[i]); }
  if (tid < N) sB[tid] = bias[tid];
  int r0 = blockIdx.x * 64;
  constexpr int CHUNKS = 64 * K / 8;
  for (int i = tid; i < CHUNKS; i += 256){
    int rr = i / (K/8); int kk = (i % (K/8)) * 8;
    int r = r0 + rr;
    ushort8 v = {0,0,0,0,0,0,0,0};
    if (r < R) v = *reinterpret_cast<const ushort8*>(in + (size_t)r*K + kk);
    *reinterpret_cast<ushort8*>(&sIn[rr][kk]) = v;
  }
  __syncthreads();
  int tx = tid & 15, ty = tid >> 4;
  float acc[4][TN];
  #pragma unroll
  for (int i=0;i<4;i++)
    #pragma unroll
    for (int j=0;j<TN;j++) acc[i][j]=0.f;
  #pragma unroll
  for (int k0 = 0; k0 < K; k0 += 8){
    ushort8 av[4], wv[TN];
    #pragma unroll
    for (int i=0;i<4;i++) av[i] = *reinterpret_cast<const ushort8*>(&sIn[ty*4+i][k0]);
    #pragma unroll
    for (int j=0;j<TN;j++) wv[j] = *reinterpret_cast<const ushort8*>(&sW[tx + 16*j][k0]);
    #pragma unroll
    for (int kk=0;kk<8;kk++){
      float a0=bf2f(av[0][kk]), a1=bf2f(av[1][kk]), a2=bf2f(av[2][kk]), a3=bf2f(av[3][kk]);
      #pragma unroll
      for (int j=0;j<TN;j++){
        float wf = bf2f(wv[j][kk]);
        acc[0][j] += a0*wf; acc[1][j] += a1*wf; acc[2][j] += a2*wf; acc[3][j] += a3*wf;
      }
    }
  }
  #pragma unroll
  for (int i=0;i<4;i++){
    int r = r0 + ty*4 + i;
    if (r >= R) continue;
    #pragma unroll
    for (int j=0;j<TN;j++){
      int c = tx + 16*j;
      float v = acc[i][j] + sB[c];
      if (RELU) v = v > 0.f ? v : 0.f;
      out[(size_t)r*N + c] = f2bf(v);
    }
  }
}

// ---- mean over V: partial sums, atomicAdd into pre-zeroed g[b][128] ----
__global__ void mean_k(const unsigned short* __restrict__ h, float* __restrict__ g, int V){
  int b = blockIdx.x;
  int chunk = blockIdx.y;
  int c = threadIdx.x & 127;
  int s = threadIdx.x >> 7; // 0..1
  int len = (V + gridDim.y - 1) / gridDim.y;
  int v0 = chunk * len;
  int v1 = min(V, v0 + len);
  float acc = 0.f;
  const unsigned short* base = h + (size_t)b*V*128 + c;
  for (int v = v0 + s; v < v1; v += 2) acc += bf2f(base[(size_t)v*128]);
  __shared__ float red[128];
  if (s == 1) red[c] = acc;
  __syncthreads();
  if (s == 0) atomicAdd(&g[b*128 + c], acc + red[c]);
}

// ---- VAE head: feat = relu(g@Wfc.T+bfc); mu; logvar(clipped); z ----
__global__ void head_k(const float* __restrict__ g, const float* __restrict__ Wfc, const float* __restrict__ bfc,
                       const float* __restrict__ Wmu, const float* __restrict__ bmu,
                       const float* __restrict__ Wlv, const float* __restrict__ blv,
                       const float* __restrict__ eps, float* __restrict__ mu_out,
                       float* __restrict__ lv_out, float* __restrict__ z_out, float invV, int Bn){
  __shared__ float sG[2048];
  __shared__ float sF[4096];
  int tid = threadIdx.x;
  for (int i = tid; i < Bn*128; i += 256) sG[i] = g[i] * invV;
  __syncthreads();
  for (int o = tid; o < Bn*256; o += 256){
    int b = o >> 8, c = o & 255;
    const float* wr = Wfc + c*128;
    const float* gr = sG + b*128;
    float acc = bfc[c];
    #pragma unroll 4
    for (int k=0;k<128;k++) acc += gr[k]*wr[k];
    sF[o] = acc > 0.f ? acc : 0.f;
  }
  __syncthreads();
  for (int o = tid; o < Bn*32; o += 256){
    int b = o >> 5, c = o & 31;
    const float* fr = sF + b*256;
    float am = bmu[c], al = blv[c];
    for (int k=0;k<256;k++){ float f = fr[k]; am += f*Wmu[c*256+k]; al += f*Wlv[c*256+k]; }
    al = fminf(20.f, fmaxf(-20.f, al));
    mu_out[o] = am; lv_out[o] = al;
    z_out[o] = am + eps[o]*expf(0.5f*al);
  }
}

// ---- decoder layer 1: concat(z[b], template[v]) (35) -> 128, ReLU, out bf16 ----
__global__ void dec1_k(const float* __restrict__ z, const float* __restrict__ tmpl,
                       const float* __restrict__ W, const float* __restrict__ b,
                       unsigned short* __restrict__ out, int V, int R, int Bn){
  __shared__ float sW[128*35];
  __shared__ float sB[128];
  __shared__ float sZ[512];
  int tid = threadIdx.x;
  for (int i = tid; i < 128*35; i += 256) sW[i] = W[i];
  if (tid < 128) sB[tid] = b[tid];
  for (int i = tid; i < Bn*32; i += 256) sZ[i] = z[i];
  __syncthreads();
  int idx = blockIdx.x*256 + tid;
  if (idx >= R*128) return;
  int c = idx & 127; int r = idx >> 7;
  int bb = r / V; int v = r - bb*V;
  const float* wr = sW + c*35;
  const float* zr = sZ + bb*32;
  float acc = sB[c];
  #pragma unroll
  for (int k=0;k<32;k++) acc += zr[k]*wr[k];
  acc += tmpl[v*3+0]*wr[32] + tmpl[v*3+1]*wr[33] + tmpl[v*3+2]*wr[34];
  out[idx] = f2bf(acc > 0.f ? acc : 0.f);
}

// ---- decoder layer 4: 64 -> 3, + template, fp32 out ----
__global__ void dec4_k(const unsigned short* __restrict__ in, const float* __restrict__ W,
                       const float* __restrict__ b, const float* __restrict__ tmpl,
                       float* __restrict__ out, int V, int R){
  __shared__ float sW[192];
  __shared__ float sB[3];
  int tid = threadIdx.x;
  if (tid < 192) sW[tid] = W[tid];
  if (tid < 3)   sB[tid] = b[tid];
  __syncthreads();
  int r = blockIdx.x*256 + tid;
  if (r >= R) return;
  int v = r % V;
  float a0 = sB[0], a1 = sB[1], a2 = sB[2];
  const unsigned short* hr = in + (size_t)r*64;
  #pragma unroll
  for (int k0 = 0; k0 < 64; k0 += 8){
    ushort8 hv = *reinterpret_cast<const ushort8*>(hr + k0);
    #pragma unroll
    for (int kk=0;kk<8;kk++){
      float h = bf2f(hv[kk]);
      a0 += h*sW[0*64 + k0+kk];
      a1 += h*sW[1*64 + k0+kk];
      a2 += h*sW[2*64 + k0+kk];
    }
  }
  out[(size_t)r*3+0] = tmpl[v*3+0] + a0;
  out[(size_t)r*3+1] = tmpl[v*3+1] + a1;
  out[(size_t)r*3+2] = tmpl[v*3+2] + a2;
}

extern "C" void kernel_launch(void* const* d_in, const int* in_sizes, int n_in,
                              void* d_out, int out_size, void* d_ws, size_t ws_size,
                              hipStream_t stream){
  const float* x    = (const float*)d_in[0];
  const float* eps  = (const float*)d_in[1];
  const int*   row  = (const int*)d_in[2];
  const int*   colx = (const int*)d_in[3];
  const float* vals = (const float*)d_in[4];
  const float* tmpl = (const float*)d_in[5];
  const float* W1 = (const float*)d_in[6];  const float* b1 = (const float*)d_in[7];
  const float* W2 = (const float*)d_in[8];  const float* b2 = (const float*)d_in[9];
  const float* W3 = (const float*)d_in[10]; const float* b3 = (const float*)d_in[11];
  const float* Wfc= (const float*)d_in[12]; const float* bfc= (const float*)d_in[13];
  const float* Wmu= (const float*)d_in[14]; const float* bmu= (const float*)d_in[15];
  const float* Wlv= (const float*)d_in[16]; const float* blv= (const float*)d_in[17];
  const float* Wd1= (const float*)d_in[18]; const float* bd1= (const float*)d_in[19];
  const float* Wd2= (const float*)d_in[20]; const float* bd2= (const float*)d_in[21];
  const float* Wd3= (const float*)d_in[22]; const float* bd3= (const float*)d_in[23];
  const float* Wd4= (const float*)d_in[24]; const float* bd4= (const float*)d_in[25];

  int V   = in_sizes[5] / 3;     // 10242
  int Bn  = in_sizes[1] / 32;    // 16
  int nnz = in_sizes[2];         // 71682
  int R   = Bn * V;              // 163872

  // workspace layout: bufA | bufB (each R*128 bf16) | row_ptr | g | z   (~84 MB)
  char* w = (char*)d_ws;
  size_t bufBytes = (size_t)R * 128 * sizeof(unsigned short);
  unsigned short* bufA = (unsigned short*)w;
  unsigned short* bufB = (unsigned short*)(w + bufBytes);
  size_t rpOff = 2*bufBytes;
  int* rp = (int*)(w + rpOff);
  size_t gOff = rpOff + (((size_t)(V+1)*4 + 255)/256)*256;
  float* g = (float*)(w + gOff);
  float* z = g + (size_t)Bn*128;

  float* recon  = (float*)d_out;
  float* mu_out = recon + (size_t)R*3;
  float* lv_out = mu_out + (size_t)Bn*32;

  rowptr_k<<<(V+1+255)/256, 256, 0, stream>>>(row, nnz, rp, V);

  // encoder
  lin1_k<<<(R*64+255)/256, 256, 0, stream>>>(x, W1, b1, bufA, R);
  spmm_relu_k<64><<<(R*64+255)/256, 256, 0, stream>>>(bufA, bufB, rp, colx, vals, Bn, V);
  lin_tiled_k<64,64,false><<<(R+63)/64, 256, 0, stream>>>(bufB, W2, b2, bufA, R);
  spmm_relu_k<64><<<(R*64+255)/256, 256, 0, stream>>>(bufA, bufB, rp, colx, vals, Bn, V);
  lin_tiled_k<64,128,false><<<(R+63)/64, 256, 0, stream>>>(bufB, W3, b3, bufA, R);
  spmm_relu_k<128><<<(R*128+255)/256, 256, 0, stream>>>(bufA, bufB, rp, colx, vals, Bn, V);

  // pool + head
  zero_k<<<(Bn*128+255)/256, 256, 0, stream>>>(g, Bn*128);
  mean_k<<<dim3(Bn, 8), 256, 0, stream>>>(bufB, g, V);
  head_k<<<1, 256, 0, stream>>>(g, Wfc, bfc, Wmu, bmu, Wlv, blv, eps,
                                mu_out, lv_out, z, 1.0f/(float)V, Bn);

  // decoder
  dec1_k<<<(R*128+255)/256, 256, 0, stream>>>(z, tmpl, Wd1, bd1, bufA, V, R, Bn);
  lin_tiled_k<128,128,true><<<(R+63)/64, 256, 0, stream>>>(bufA, Wd2, bd2, bufB, R);
  lin_tiled_k<128,64,true><<<(R+63)/64, 256, 0, stream>>>(bufB, Wd3, bd3, bufA, R);
  dec4_k<<<(R+255)/256, 256, 0, stream>>>(bufA, Wd4, bd4, tmpl, recon, V, R);
}

// Round 2
// 856.368 us; speedup vs baseline: 10.0458x; 10.0458x over previous
//
#include <hip/hip_runtime.h>
#include <hip/hip_bf16.h>

typedef __attribute__((ext_vector_type(8))) unsigned short ushort8;
typedef __attribute__((ext_vector_type(4))) unsigned short ushort4v;
typedef __attribute__((ext_vector_type(8))) short short8v;
typedef __attribute__((ext_vector_type(4))) float f32x4;

__device__ __forceinline__ float bf2f(unsigned short u){
  union { unsigned int i; float f; } x; x.i = ((unsigned int)u) << 16; return x.f;
}
__device__ __forceinline__ unsigned short f2bf(float f){
  __hip_bfloat16 h = __float2bfloat16(f);
  return *reinterpret_cast<unsigned short*>(&h);
}

// ---- CSR row_ptr via binary search over sorted row[] ----
__global__ void rowptr_k(const int* __restrict__ row, int nnz, int* __restrict__ rp, int V){
  int v = blockIdx.x*blockDim.x + threadIdx.x;
  if (v > V) return;
  int lo = 0, hi = nnz;
  while (lo < hi){ int m = (lo+hi)>>1; if (row[m] < v) lo = m+1; else hi = m; }
  rp[v] = lo;
}

// ---- zero small buffer ----
__global__ void zero_k(float* __restrict__ p, int n){
  int i = blockIdx.x*blockDim.x + threadIdx.x;
  if (i < n) p[i] = 0.f;
}

// ---- encoder linear 1 (3 -> 64) + bias, out bf16 ----
__global__ void lin1_k(const float* __restrict__ x, const float* __restrict__ W,
                       const float* __restrict__ b, unsigned short* __restrict__ out, int R){
  __shared__ float sW[192];
  __shared__ float sB[64];
  int tid = threadIdx.x;
  if (tid < 192) sW[tid] = W[tid];
  if (tid < 64)  sB[tid] = b[tid];
  __syncthreads();
  int idx = blockIdx.x*256 + tid;
  if (idx >= R*64) return;
  int c = idx & 63, r = idx >> 6;
  const float* xr = x + (size_t)r*3;
  float acc = sB[c] + xr[0]*sW[c*3+0] + xr[1]*sW[c*3+1] + xr[2]*sW[c*3+2];
  out[idx] = f2bf(acc);
}

// ---- SPMM (normalized adjacency) + ReLU, bf16 in/out, fp32 accum ----
template<int C>
__global__ void spmm_relu_k(const unsigned short* __restrict__ in, unsigned short* __restrict__ out,
                            const int* __restrict__ rp, const int* __restrict__ colx,
                            const float* __restrict__ vals, int Bn, int V){
  int idx = blockIdx.x*256 + threadIdx.x;
  if (idx >= Bn*V*C) return;
  int c = idx % C; int v = (idx / C) % V; int b = idx / (C*V);
  const unsigned short* base = in + (size_t)b*V*C;
  float acc = 0.f;
  int e1 = rp[v+1];
  for (int e = rp[v]; e < e1; ++e){
    acc += vals[e] * bf2f(base[(size_t)colx[e]*C + c]);
  }
  out[idx] = f2bf(acc > 0.f ? acc : 0.f);
}

// ---- MFMA dense linear: out[R,N] = in[R,K](bf16) @ W[N,K]^T + b, opt ReLU, out bf16 ----
// Swapped orientation: A = W (staged bf16 in LDS, +8 pad -> 2-way bank alias, free),
// B = input rows straight from global (16B dwordx4, read exactly once).
// Block = 4 waves x 32 rows = 128 rows. Wave: NF x 2 f32x4 acc frags.
template<int K, int N, bool RELU>
__global__ __launch_bounds__(256) void lin_mfma_k(const unsigned short* __restrict__ in,
    const float* __restrict__ W, const float* __restrict__ bias,
    unsigned short* __restrict__ out, int R){
  constexpr int KP = K + 8;
  constexpr int NF = N / 16;
  constexpr int KS = K / 32;
  __shared__ unsigned short sW[N * KP];
  __shared__ float sB[N];
  int tid = threadIdx.x;
  // stage W fp32 -> bf16 (vector float4 reads; k%4==0 keeps 8B-aligned LDS stores)
  for (int i = tid*4; i < N*K; i += 1024){
    const float4 wv = *reinterpret_cast<const float4*>(W + i);
    int n = i / K, k = i - n*K;
    unsigned short* dst = &sW[n*KP + k];
    dst[0] = f2bf(wv.x); dst[1] = f2bf(wv.y); dst[2] = f2bf(wv.z); dst[3] = f2bf(wv.w);
  }
  if (tid < N) sB[tid] = bias[tid];
  __syncthreads();

  const int wave = tid >> 6, lane = tid & 63;
  const int l15 = lane & 15, lg = lane >> 4;      // lg = k-group 0..3
  const int rbase = blockIdx.x*128 + wave*32;

  // B (input) row pointers, clamped for the tail block (garbage stays in unwritten lanes)
  int r0c = min(rbase + l15,      R-1);
  int r1c = min(rbase + 16 + l15, R-1);
  const unsigned short* bp0 = in + (size_t)r0c*K + lg*8;
  const unsigned short* bp1 = in + (size_t)r1c*K + lg*8;
  const unsigned short* aBase = &sW[l15*KP + lg*8];

  f32x4 acc[NF][2];
  #pragma unroll
  for (int nf=0; nf<NF; ++nf){ acc[nf][0] = (f32x4)0.f; acc[nf][1] = (f32x4)0.f; }

  #pragma unroll
  for (int ks=0; ks<KS; ++ks){
    short8v b0 = *reinterpret_cast<const short8v*>(bp0 + ks*32);
    short8v b1 = *reinterpret_cast<const short8v*>(bp1 + ks*32);
    #pragma unroll
    for (int nf=0; nf<NF; ++nf){
      short8v a = *reinterpret_cast<const short8v*>(aBase + nf*16*KP + ks*32);
      acc[nf][0] = __builtin_amdgcn_mfma_f32_16x16x32_bf16(a, b0, acc[nf][0], 0,0,0);
      acc[nf][1] = __builtin_amdgcn_mfma_f32_16x16x32_bf16(a, b1, acc[nf][1], 0,0,0);
    }
  }

  // C/D frag: col = l15 -> row r; row = 4*lg + reg -> 4 consecutive n => 8B packed store
  #pragma unroll
  for (int rr=0; rr<2; ++rr){
    int r = rbase + rr*16 + l15;
    if (r >= R) continue;
    #pragma unroll
    for (int nf=0; nf<NF; ++nf){
      int nb = nf*16 + lg*4;
      ushort4v o;
      #pragma unroll
      for (int reg=0; reg<4; ++reg){
        float v = acc[nf][rr][reg] + sB[nb + reg];
        if (RELU) v = v > 0.f ? v : 0.f;
        o[reg] = f2bf(v);
      }
      *reinterpret_cast<ushort4v*>(out + (size_t)r*N + nb) = o;
    }
  }
}

// ---- mean over V: partial sums, atomicAdd into pre-zeroed g[b][128] ----
__global__ void mean_k(const unsigned short* __restrict__ h, float* __restrict__ g, int V){
  int b = blockIdx.x;
  int chunk = blockIdx.y;
  int c = threadIdx.x & 127;
  int s = threadIdx.x >> 7; // 0..1
  int len = (V + gridDim.y - 1) / gridDim.y;
  int v0 = chunk * len;
  int v1 = min(V, v0 + len);
  float acc = 0.f;
  const unsigned short* base = h + (size_t)b*V*128 + c;
  for (int v = v0 + s; v < v1; v += 2) acc += bf2f(base[(size_t)v*128]);
  __shared__ float red[128];
  if (s == 1) red[c] = acc;
  __syncthreads();
  if (s == 0) atomicAdd(&g[b*128 + c], acc + red[c]);
}

// ---- VAE head: feat = relu(g@Wfc.T+bfc); mu; logvar(clipped); z ----
__global__ void head_k(const float* __restrict__ g, const float* __restrict__ Wfc, const float* __restrict__ bfc,
                       const float* __restrict__ Wmu, const float* __restrict__ bmu,
                       const float* __restrict__ Wlv, const float* __restrict__ blv,
                       const float* __restrict__ eps, float* __restrict__ mu_out,
                       float* __restrict__ lv_out, float* __restrict__ z_out, float invV, int Bn){
  __shared__ float sG[2048];
  __shared__ float sF[4096];
  int tid = threadIdx.x;
  for (int i = tid; i < Bn*128; i += 256) sG[i] = g[i] * invV;
  __syncthreads();
  for (int o = tid; o < Bn*256; o += 256){
    int b = o >> 8, c = o & 255;
    const float* wr = Wfc + c*128;
    const float* gr = sG + b*128;
    float acc = bfc[c];
    #pragma unroll 4
    for (int k=0;k<128;k++) acc += gr[k]*wr[k];
    sF[o] = acc > 0.f ? acc : 0.f;
  }
  __syncthreads();
  for (int o = tid; o < Bn*32; o += 256){
    int b = o >> 5, c = o & 31;
    const float* fr = sF + b*256;
    float am = bmu[c], al = blv[c];
    for (int k=0;k<256;k++){ float f = fr[k]; am += f*Wmu[c*256+k]; al += f*Wlv[c*256+k]; }
    al = fminf(20.f, fmaxf(-20.f, al));
    mu_out[o] = am; lv_out[o] = al;
    z_out[o] = am + eps[o]*expf(0.5f*al);
  }
}

// ---- decoder layer 1: concat(z[b], template[v]) (35) -> 128, ReLU, out bf16 ----
__global__ void dec1_k(const float* __restrict__ z, const float* __restrict__ tmpl,
                       const float* __restrict__ W, const float* __restrict__ b,
                       unsigned short* __restrict__ out, int V, int R, int Bn){
  __shared__ float sW[128*35];
  __shared__ float sB[128];
  __shared__ float sZ[512];
  int tid = threadIdx.x;
  for (int i = tid; i < 128*35; i += 256) sW[i] = W[i];
  if (tid < 128) sB[tid] = b[tid];
  for (int i = tid; i < Bn*32; i += 256) sZ[i] = z[i];
  __syncthreads();
  int idx = blockIdx.x*256 + tid;
  if (idx >= R*128) return;
  int c = idx & 127; int r = idx >> 7;
  int bb = r / V; int v = r - bb*V;
  const float* wr = sW + c*35;
  const float* zr = sZ + bb*32;
  float acc = sB[c];
  #pragma unroll
  for (int k=0;k<32;k++) acc += zr[k]*wr[k];
  acc += tmpl[v*3+0]*wr[32] + tmpl[v*3+1]*wr[33] + tmpl[v*3+2]*wr[34];
  out[idx] = f2bf(acc > 0.f ? acc : 0.f);
}

// ---- decoder layer 4: 64 -> 3, + template, fp32 out ----
__global__ void dec4_k(const unsigned short* __restrict__ in, const float* __restrict__ W,
                       const float* __restrict__ b, const float* __restrict__ tmpl,
                       float* __restrict__ out, int V, int R){
  __shared__ float sW[192];
  __shared__ float sB[3];
  int tid = threadIdx.x;
  if (tid < 192) sW[tid] = W[tid];
  if (tid < 3)   sB[tid] = b[tid];
  __syncthreads();
  int r = blockIdx.x*256 + tid;
  if (r >= R) return;
  int v = r % V;
  float a0 = sB[0], a1 = sB[1], a2 = sB[2];
  const unsigned short* hr = in + (size_t)r*64;
  #pragma unroll
  for (int k0 = 0; k0 < 64; k0 += 8){
    ushort8 hv = *reinterpret_cast<const ushort8*>(hr + k0);
    #pragma unroll
    for (int kk=0;kk<8;kk++){
      float h = bf2f(hv[kk]);
      a0 += h*sW[0*64 + k0+kk];
      a1 += h*sW[1*64 + k0+kk];
      a2 += h*sW[2*64 + k0+kk];
    }
  }
  out[(size_t)r*3+0] = tmpl[v*3+0] + a0;
  out[(size_t)r*3+1] = tmpl[v*3+1] + a1;
  out[(size_t)r*3+2] = tmpl[v*3+2] + a2;
}

extern "C" void kernel_launch(void* const* d_in, const int* in_sizes, int n_in,
                              void* d_out, int out_size, void* d_ws, size_t ws_size,
                              hipStream_t stream){
  const float* x    = (const float*)d_in[0];
  const float* eps  = (const float*)d_in[1];
  const int*   row  = (const int*)d_in[2];
  const int*   colx = (const int*)d_in[3];
  const float* vals = (const float*)d_in[4];
  const float* tmpl = (const float*)d_in[5];
  const float* W1 = (const float*)d_in[6];  const float* b1 = (const float*)d_in[7];
  const float* W2 = (const float*)d_in[8];  const float* b2 = (const float*)d_in[9];
  const float* W3 = (const float*)d_in[10]; const float* b3 = (const float*)d_in[11];
  const float* Wfc= (const float*)d_in[12]; const float* bfc= (const float*)d_in[13];
  const float* Wmu= (const float*)d_in[14]; const float* bmu= (const float*)d_in[15];
  const float* Wlv= (const float*)d_in[16]; const float* blv= (const float*)d_in[17];
  const float* Wd1= (const float*)d_in[18]; const float* bd1= (const float*)d_in[19];
  const float* Wd2= (const float*)d_in[20]; const float* bd2= (const float*)d_in[21];
  const float* Wd3= (const float*)d_in[22]; const float* bd3= (const float*)d_in[23];
  const float* Wd4= (const float*)d_in[24]; const float* bd4= (const float*)d_in[25];

  int V   = in_sizes[5] / 3;     // 10242
  int Bn  = in_sizes[1] / 32;    // 16
  int nnz = in_sizes[2];         // 71682
  int R   = Bn * V;              // 163872

  // workspace layout: bufA | bufB (each R*128 bf16) | row_ptr | g | z   (~84 MB)
  char* w = (char*)d_ws;
  size_t bufBytes = (size_t)R * 128 * sizeof(unsigned short);
  unsigned short* bufA = (unsigned short*)w;
  unsigned short* bufB = (unsigned short*)(w + bufBytes);
  size_t rpOff = 2*bufBytes;
  int* rp = (int*)(w + rpOff);
  size_t gOff = rpOff + (((size_t)(V+1)*4 + 255)/256)*256;
  float* g = (float*)(w + gOff);
  float* z = g + (size_t)Bn*128;

  float* recon  = (float*)d_out;
  float* mu_out = recon + (size_t)R*3;
  float* lv_out = mu_out + (size_t)Bn*32;

  int mfmaGrid = (R + 127) / 128;

  rowptr_k<<<(V+1+255)/256, 256, 0, stream>>>(row, nnz, rp, V);

  // encoder
  lin1_k<<<(R*64+255)/256, 256, 0, stream>>>(x, W1, b1, bufA, R);
  spmm_relu_k<64><<<(R*64+255)/256, 256, 0, stream>>>(bufA, bufB, rp, colx, vals, Bn, V);
  lin_mfma_k<64,64,false><<<mfmaGrid, 256, 0, stream>>>(bufB, W2, b2, bufA, R);
  spmm_relu_k<64><<<(R*64+255)/256, 256, 0, stream>>>(bufA, bufB, rp, colx, vals, Bn, V);
  lin_mfma_k<64,128,false><<<mfmaGrid, 256, 0, stream>>>(bufB, W3, b3, bufA, R);
  spmm_relu_k<128><<<(R*128+255)/256, 256, 0, stream>>>(bufA, bufB, rp, colx, vals, Bn, V);

  // pool + head
  zero_k<<<(Bn*128+255)/256, 256, 0, stream>>>(g, Bn*128);
  mean_k<<<dim3(Bn, 8), 256, 0, stream>>>(bufB, g, V);
  head_k<<<1, 256, 0, stream>>>(g, Wfc, bfc, Wmu, bmu, Wlv, blv, eps,
                                mu_out, lv_out, z, 1.0f/(float)V, Bn);

  // decoder
  dec1_k<<<(R*128+255)/256, 256, 0, stream>>>(z, tmpl, Wd1, bd1, bufA, V, R, Bn);
  lin_mfma_k<128,128,true><<<mfmaGrid, 256, 0, stream>>>(bufA, Wd2, bd2, bufB, R);
  lin_mfma_k<128,64,true><<<mfmaGrid, 256, 0, stream>>>(bufB, Wd3, bd3, bufA, R);
  dec4_k<<<(R+255)/256, 256, 0, stream>>>(bufA, Wd4, bd4, tmpl, recon, V, R);
}

// Round 3
// 302.120 us; speedup vs baseline: 28.4751x; 2.8345x over previous
//
#include <hip/hip_runtime.h>
#include <hip/hip_bf16.h>

typedef __attribute__((ext_vector_type(8))) unsigned short ushort8;
typedef __attribute__((ext_vector_type(4))) unsigned short ushort4v;
typedef __attribute__((ext_vector_type(8))) short short8v;
typedef __attribute__((ext_vector_type(4))) float f32x4;

__device__ __forceinline__ float bf2f(unsigned short u){
  union { unsigned int i; float f; } x; x.i = ((unsigned int)u) << 16; return x.f;
}
__device__ __forceinline__ unsigned short f2bf(float f){
  __hip_bfloat16 h = __float2bfloat16(f);
  return *reinterpret_cast<unsigned short*>(&h);
}

// ---- CSR row_ptr via binary search over sorted row[] ----
__global__ void rowptr_k(const int* __restrict__ row, int nnz, int* __restrict__ rp, int V){
  int v = blockIdx.x*blockDim.x + threadIdx.x;
  if (v > V) return;
  int lo = 0, hi = nnz;
  while (lo < hi){ int m = (lo+hi)>>1; if (row[m] < v) lo = m+1; else hi = m; }
  rp[v] = lo;
}

// ---- pad edges to fixed degree 7 (icosphere max deg = 6 nbrs + self), rowsum d ----
__global__ void pad7_k(const int* __restrict__ rp, const int* __restrict__ colx,
                       const float* __restrict__ vals, int* __restrict__ col7,
                       float* __restrict__ val7, float* __restrict__ d, int V){
  int v = blockIdx.x*256 + threadIdx.x;
  if (v >= V) return;
  int e0 = rp[v], e1 = rp[v+1];
  float s = 0.f;
  #pragma unroll
  for (int i=0;i<7;i++){
    int e = e0 + i;
    int c  = (e < e1) ? colx[e] : 0;
    float w = (e < e1) ? vals[e] : 0.f;
    col7[v*7+i] = c; val7[v*7+i] = w; s += w;
  }
  d[v] = s;
}

// ---- zero small buffer ----
__global__ void zero_k(float* __restrict__ p, int n){
  int i = blockIdx.x*blockDim.x + threadIdx.x;
  if (i < n) p[i] = 0.f;
}

// ---- fused: s = spmm(x) over C=3, then h1 = relu(s@W1^T + d[v]*b1), bf16 out ----
__global__ void spmm_lin1_k(const float* __restrict__ x, const int* __restrict__ col7,
    const float* __restrict__ val7, const float* __restrict__ d,
    const float* __restrict__ W1, const float* __restrict__ b1,
    unsigned short* __restrict__ out, int V, int R){
  __shared__ float sW[192];
  __shared__ float sB[64];
  int tid = threadIdx.x;
  if (tid < 192) sW[tid] = W1[tid];
  if (tid < 64)  sB[tid] = b1[tid];
  __syncthreads();
  int r = blockIdx.x*256 + tid;
  if (r >= R) return;
  int b = r / V; int v = r - b*V;
  const float* xb = x + (size_t)b*V*3;
  int   cs[7]; float ws[7];
  #pragma unroll
  for (int i=0;i<7;i++){ cs[i] = col7[v*7+i]; ws[i] = val7[v*7+i]; }
  float s0=0.f, s1=0.f, s2=0.f;
  #pragma unroll
  for (int i=0;i<7;i++){
    const float* xr = xb + (size_t)cs[i]*3;
    s0 += ws[i]*xr[0]; s1 += ws[i]*xr[1]; s2 += ws[i]*xr[2];
  }
  float dv = d[v];
  unsigned short* orow = out + (size_t)r*64;
  #pragma unroll
  for (int cg=0; cg<8; ++cg){
    ushort8 o;
    #pragma unroll
    for (int k=0;k<8;k++){
      int c = cg*8 + k;
      float acc = dv*sB[c] + s0*sW[c*3] + s1*sW[c*3+1] + s2*sW[c*3+2];
      o[k] = f2bf(fmaxf(acc, 0.f));
    }
    *reinterpret_cast<ushort8*>(orow + cg*8) = o;
  }
}

// ---- SPMM, fixed-degree-7 unrolled, 8 channels/thread (16B gathers, full MLP) ----
template<int C>
__global__ __launch_bounds__(256) void spmm8_k(const unsigned short* __restrict__ in,
    unsigned short* __restrict__ out, const int* __restrict__ col7,
    const float* __restrict__ val7, int Bn, int V){
  constexpr int CG = C/8;
  int idx = blockIdx.x*256 + threadIdx.x;
  if (idx >= Bn*V*CG) return;
  int cg = idx % CG; int v = (idx/CG) % V; int b = idx/(CG*V);
  const unsigned short* base = in + (size_t)b*V*C + cg*8;
  int cols[7]; float vv[7];
  #pragma unroll
  for (int i=0;i<7;i++){ cols[i] = col7[v*7+i]; vv[i] = val7[v*7+i]; }
  ushort8 g[7];
  #pragma unroll
  for (int i=0;i<7;i++) g[i] = *reinterpret_cast<const ushort8*>(base + (size_t)cols[i]*C);
  float acc[8];
  #pragma unroll
  for (int k=0;k<8;k++) acc[k] = 0.f;
  #pragma unroll
  for (int i=0;i<7;i++){
    float s = vv[i];
    #pragma unroll
    for (int k=0;k<8;k++) acc[k] += s*bf2f(g[i][k]);
  }
  ushort8 o;
  #pragma unroll
  for (int k=0;k<8;k++) o[k] = f2bf(acc[k]);
  *reinterpret_cast<ushort8*>(out + (size_t)idx*8) = o;
}

// ---- MFMA dense linear: out[R,N] = in[R,K](bf16) @ W[N,K]^T + bias*(d[v] or 1), opt ReLU ----
template<int K, int N, bool RELU, bool DBIAS>
__global__ __launch_bounds__(256) void lin_mfma_k(const unsigned short* __restrict__ in,
    const float* __restrict__ W, const float* __restrict__ bias,
    unsigned short* __restrict__ out, int R, const float* __restrict__ dvec, int V){
  constexpr int KP = K + 8;
  constexpr int NF = N / 16;
  constexpr int KS = K / 32;
  __shared__ unsigned short sW[N * KP];
  __shared__ float sB[N];
  int tid = threadIdx.x;
  for (int i = tid*4; i < N*K; i += 1024){
    const float4 wv = *reinterpret_cast<const float4*>(W + i);
    int n = i / K, k = i - n*K;
    unsigned short* dst = &sW[n*KP + k];
    dst[0] = f2bf(wv.x); dst[1] = f2bf(wv.y); dst[2] = f2bf(wv.z); dst[3] = f2bf(wv.w);
  }
  if (tid < N) sB[tid] = bias[tid];
  __syncthreads();

  const int wave = tid >> 6, lane = tid & 63;
  const int l15 = lane & 15, lg = lane >> 4;
  const int rbase = blockIdx.x*128 + wave*32;

  int r0c = min(rbase + l15,      R-1);
  int r1c = min(rbase + 16 + l15, R-1);
  const unsigned short* bp0 = in + (size_t)r0c*K + lg*8;
  const unsigned short* bp1 = in + (size_t)r1c*K + lg*8;
  const unsigned short* aBase = &sW[l15*KP + lg*8];

  f32x4 acc[NF][2];
  #pragma unroll
  for (int nf=0; nf<NF; ++nf){ acc[nf][0] = (f32x4)0.f; acc[nf][1] = (f32x4)0.f; }

  #pragma unroll
  for (int ks=0; ks<KS; ++ks){
    short8v b0 = *reinterpret_cast<const short8v*>(bp0 + ks*32);
    short8v b1 = *reinterpret_cast<const short8v*>(bp1 + ks*32);
    #pragma unroll
    for (int nf=0; nf<NF; ++nf){
      short8v a = *reinterpret_cast<const short8v*>(aBase + nf*16*KP + ks*32);
      acc[nf][0] = __builtin_amdgcn_mfma_f32_16x16x32_bf16(a, b0, acc[nf][0], 0,0,0);
      acc[nf][1] = __builtin_amdgcn_mfma_f32_16x16x32_bf16(a, b1, acc[nf][1], 0,0,0);
    }
  }

  #pragma unroll
  for (int rr=0; rr<2; ++rr){
    int r = rbase + rr*16 + l15;
    if (r >= R) continue;
    float bscale = 1.f;
    if (DBIAS){ int vv = r % V; bscale = dvec[vv]; }
    #pragma unroll
    for (int nf=0; nf<NF; ++nf){
      int nb = nf*16 + lg*4;
      ushort4v o;
      #pragma unroll
      for (int reg=0; reg<4; ++reg){
        float v = acc[nf][rr][reg] + bscale*sB[nb + reg];
        if (RELU) v = v > 0.f ? v : 0.f;
        o[reg] = f2bf(v);
      }
      *reinterpret_cast<ushort4v*>(out + (size_t)r*N + nb) = o;
    }
  }
}

// ---- mean over V: partial sums, atomicAdd into pre-zeroed g[b][128] ----
__global__ void mean_k(const unsigned short* __restrict__ h, float* __restrict__ g, int V){
  int b = blockIdx.x;
  int chunk = blockIdx.y;
  int c = threadIdx.x & 127;
  int s = threadIdx.x >> 7;
  int len = (V + gridDim.y - 1) / gridDim.y;
  int v0 = chunk * len;
  int v1 = min(V, v0 + len);
  float acc = 0.f;
  const unsigned short* base = h + (size_t)b*V*128 + c;
  for (int v = v0 + s; v < v1; v += 2) acc += bf2f(base[(size_t)v*128]);
  __shared__ float red[128];
  if (s == 1) red[c] = acc;
  __syncthreads();
  if (s == 0) atomicAdd(&g[b*128 + c], acc + red[c]);
}

// ---- VAE head ----
__global__ void head_k(const float* __restrict__ g, const float* __restrict__ Wfc, const float* __restrict__ bfc,
                       const float* __restrict__ Wmu, const float* __restrict__ bmu,
                       const float* __restrict__ Wlv, const float* __restrict__ blv,
                       const float* __restrict__ eps, float* __restrict__ mu_out,
                       float* __restrict__ lv_out, float* __restrict__ z_out, float invV, int Bn){
  __shared__ float sG[2048];
  __shared__ float sF[4096];
  int tid = threadIdx.x;
  for (int i = tid; i < Bn*128; i += 256) sG[i] = g[i] * invV;
  __syncthreads();
  for (int o = tid; o < Bn*256; o += 256){
    int b = o >> 8, c = o & 255;
    const float* wr = Wfc + c*128;
    const float* gr = sG + b*128;
    float acc = bfc[c];
    #pragma unroll 4
    for (int k=0;k<128;k++) acc += gr[k]*wr[k];
    sF[o] = acc > 0.f ? acc : 0.f;
  }
  __syncthreads();
  for (int o = tid; o < Bn*32; o += 256){
    int b = o >> 5, c = o & 31;
    const float* fr = sF + b*256;
    float am = bmu[c], al = blv[c];
    for (int k=0;k<256;k++){ float f = fr[k]; am += f*Wmu[c*256+k]; al += f*Wlv[c*256+k]; }
    al = fminf(20.f, fmaxf(-20.f, al));
    mu_out[o] = am; lv_out[o] = al;
    z_out[o] = am + eps[o]*expf(0.5f*al);
  }
}

// ---- zpart[b][c] = bd1[c] + z[b,:32] @ Wd1[c,:32] ----
__global__ void zpart_k(const float* __restrict__ z, const float* __restrict__ Wd1,
                        const float* __restrict__ bd1, float* __restrict__ zp, int Bn){
  int o = blockIdx.x*256 + threadIdx.x;
  if (o >= Bn*128) return;
  int b = o >> 7, c = o & 127;
  const float* wr = Wd1 + c*35;
  const float* zr = z + b*32;
  float acc = bd1[c];
  #pragma unroll
  for (int k=0;k<32;k++) acc += zr[k]*wr[k];
  zp[o] = acc;
}

// ---- tpart[v][c] = tmpl[v,:] @ Wd1[c,32:35]  (bf16) ----
__global__ void tpart_k(const float* __restrict__ tmpl, const float* __restrict__ Wd1,
                        unsigned short* __restrict__ tp, int V){
  int o = blockIdx.x*256 + threadIdx.x;
  if (o >= V*128) return;
  int v = o >> 7, c = o & 127;
  const float* wr = Wd1 + c*35 + 32;
  float t = tmpl[v*3]*wr[0] + tmpl[v*3+1]*wr[1] + tmpl[v*3+2]*wr[2];
  tp[o] = f2bf(t);
}

// ---- dec1: hd = relu(zpart[b] + tpart[v]), elementwise, bf16 out ----
__global__ void dec1_elt_k(const float* __restrict__ zp, const unsigned short* __restrict__ tp,
                           unsigned short* __restrict__ out, int V, int R){
  int idx = blockIdx.x*256 + threadIdx.x;
  if (idx >= R*16) return;
  int cg = idx & 15; int r = idx >> 4;
  int b = r / V; int v = r - b*V;
  const float* za = zp + b*128 + cg*8;
  ushort8 t = *reinterpret_cast<const ushort8*>(tp + (size_t)v*128 + cg*8);
  ushort8 o;
  #pragma unroll
  for (int k=0;k<8;k++){
    float val = za[k] + bf2f(t[k]);
    o[k] = f2bf(fmaxf(val, 0.f));
  }
  *reinterpret_cast<ushort8*>(out + (size_t)idx*8) = o;
}

// ---- decoder layer 4: 64 -> 3, + template, fp32 out ----
__global__ void dec4_k(const unsigned short* __restrict__ in, const float* __restrict__ W,
                       const float* __restrict__ b, const float* __restrict__ tmpl,
                       float* __restrict__ out, int V, int R){
  __shared__ float sW[192];
  __shared__ float sB[3];
  int tid = threadIdx.x;
  if (tid < 192) sW[tid] = W[tid];
  if (tid < 3)   sB[tid] = b[tid];
  __syncthreads();
  int r = blockIdx.x*256 + tid;
  if (r >= R) return;
  int v = r % V;
  float a0 = sB[0], a1 = sB[1], a2 = sB[2];
  const unsigned short* hr = in + (size_t)r*64;
  #pragma unroll
  for (int k0 = 0; k0 < 64; k0 += 8){
    ushort8 hv = *reinterpret_cast<const ushort8*>(hr + k0);
    #pragma unroll
    for (int kk=0;kk<8;kk++){
      float h = bf2f(hv[kk]);
      a0 += h*sW[0*64 + k0+kk];
      a1 += h*sW[1*64 + k0+kk];
      a2 += h*sW[2*64 + k0+kk];
    }
  }
  out[(size_t)r*3+0] = tmpl[v*3+0] + a0;
  out[(size_t)r*3+1] = tmpl[v*3+1] + a1;
  out[(size_t)r*3+2] = tmpl[v*3+2] + a2;
}

extern "C" void kernel_launch(void* const* d_in, const int* in_sizes, int n_in,
                              void* d_out, int out_size, void* d_ws, size_t ws_size,
                              hipStream_t stream){
  const float* x    = (const float*)d_in[0];
  const float* eps  = (const float*)d_in[1];
  const int*   row  = (const int*)d_in[2];
  const int*   colx = (const int*)d_in[3];
  const float* vals = (const float*)d_in[4];
  const float* tmpl = (const float*)d_in[5];
  const float* W1 = (const float*)d_in[6];  const float* b1 = (const float*)d_in[7];
  const float* W2 = (const float*)d_in[8];  const float* b2 = (const float*)d_in[9];
  const float* W3 = (const float*)d_in[10]; const float* b3 = (const float*)d_in[11];
  const float* Wfc= (const float*)d_in[12]; const float* bfc= (const float*)d_in[13];
  const float* Wmu= (const float*)d_in[14]; const float* bmu= (const float*)d_in[15];
  const float* Wlv= (const float*)d_in[16]; const float* blv= (const float*)d_in[17];
  const float* Wd1= (const float*)d_in[18]; const float* bd1= (const float*)d_in[19];
  const float* Wd2= (const float*)d_in[20]; const float* bd2= (const float*)d_in[21];
  const float* Wd3= (const float*)d_in[22]; const float* bd3= (const float*)d_in[23];
  const float* Wd4= (const float*)d_in[24]; const float* bd4= (const float*)d_in[25];

  int V   = in_sizes[5] / 3;     // 10242
  int Bn  = in_sizes[1] / 32;    // 16
  int nnz = in_sizes[2];         // 71682
  int R   = Bn * V;              // 163872

  // workspace layout
  char* w = (char*)d_ws;
  size_t off = 0;
  auto alloc = [&](size_t bytes)->char*{
    char* p = w + off; off = (off + bytes + 255) & ~(size_t)255; return p;
  };
  size_t bufBytes = (size_t)R * 128 * sizeof(unsigned short);
  unsigned short* bufA = (unsigned short*)alloc(bufBytes);
  unsigned short* bufB = (unsigned short*)alloc(bufBytes);
  int*   rp   = (int*)alloc((size_t)(V+1)*4);
  int*   col7 = (int*)alloc((size_t)V*7*4);
  float* val7 = (float*)alloc((size_t)V*7*4);
  float* dvec = (float*)alloc((size_t)V*4);
  float* g    = (float*)alloc((size_t)Bn*128*4);
  float* z    = (float*)alloc((size_t)Bn*32*4);
  float* zp   = (float*)alloc((size_t)Bn*128*4);
  unsigned short* tp = (unsigned short*)alloc((size_t)V*128*2);

  float* recon  = (float*)d_out;
  float* mu_out = recon + (size_t)R*3;
  float* lv_out = mu_out + (size_t)Bn*32;

  int mfmaGrid = (R + 127) / 128;

  // graph prep
  rowptr_k<<<(V+1+255)/256, 256, 0, stream>>>(row, nnz, rp, V);
  pad7_k<<<(V+255)/256, 256, 0, stream>>>(rp, colx, vals, col7, val7, dvec, V);

  // encoder (spmm/linear reordered: lin(spmm(h)) with d-scaled bias)
  spmm_lin1_k<<<(R+255)/256, 256, 0, stream>>>(x, col7, val7, dvec, W1, b1, bufA, V, R);
  spmm8_k<64><<<(R*8+255)/256, 256, 0, stream>>>(bufA, bufB, col7, val7, Bn, V);
  lin_mfma_k<64,64,true,true><<<mfmaGrid, 256, 0, stream>>>(bufB, W2, b2, bufA, R, dvec, V);
  spmm8_k<64><<<(R*8+255)/256, 256, 0, stream>>>(bufA, bufB, col7, val7, Bn, V);
  lin_mfma_k<64,128,true,true><<<mfmaGrid, 256, 0, stream>>>(bufB, W3, b3, bufA, R, dvec, V);

  // pool + head
  zero_k<<<(Bn*128+255)/256, 256, 0, stream>>>(g, Bn*128);
  mean_k<<<dim3(Bn, 32), 256, 0, stream>>>(bufA, g, V);
  head_k<<<1, 256, 0, stream>>>(g, Wfc, bfc, Wmu, bmu, Wlv, blv, eps,
                                mu_out, lv_out, z, 1.0f/(float)V, Bn);

  // decoder
  zpart_k<<<(Bn*128+255)/256, 256, 0, stream>>>(z, Wd1, bd1, zp, Bn);
  tpart_k<<<(V*128+255)/256, 256, 0, stream>>>(tmpl, Wd1, tp, V);
  dec1_elt_k<<<(R*16+255)/256, 256, 0, stream>>>(zp, tp, bufB, V, R);
  lin_mfma_k<128,128,true,false><<<mfmaGrid, 256, 0, stream>>>(bufB, Wd2, bd2, bufA, R, nullptr, V);
  lin_mfma_k<128,64,true,false><<<mfmaGrid, 256, 0, stream>>>(bufA, Wd3, bd3, bufB, R, nullptr, V);
  dec4_k<<<(R+255)/256, 256, 0, stream>>>(bufB, Wd4, bd4, tmpl, recon, V, R);
}

// Round 4
// 220.095 us; speedup vs baseline: 39.0871x; 1.3727x over previous
//
#include <hip/hip_runtime.h>
#include <hip/hip_bf16.h>

typedef __attribute__((ext_vector_type(8))) unsigned short ushort8;
typedef __attribute__((ext_vector_type(4))) unsigned short ushort4v;
typedef __attribute__((ext_vector_type(8))) short short8v;
typedef __attribute__((ext_vector_type(4))) float f32x4;

__device__ __forceinline__ float bf2f(unsigned short u){
  union { unsigned int i; float f; } x; x.i = ((unsigned int)u) << 16; return x.f;
}
__device__ __forceinline__ unsigned short f2bf(float f){
  __hip_bfloat16 h = __float2bfloat16(f);
  return *reinterpret_cast<unsigned short*>(&h);
}

// ---- CSR row_ptr via binary search over sorted row[] ----
__global__ void rowptr_k(const int* __restrict__ row, int nnz, int* __restrict__ rp, int V){
  int v = blockIdx.x*blockDim.x + threadIdx.x;
  if (v > V) return;
  int lo = 0, hi = nnz;
  while (lo < hi){ int m = (lo+hi)>>1; if (row[m] < v) lo = m+1; else hi = m; }
  rp[v] = lo;
}

// ---- pad edges to fixed degree 7 (icosphere max deg = 6 nbrs + self), rowsum d ----
__global__ void pad7_k(const int* __restrict__ rp, const int* __restrict__ colx,
                       const float* __restrict__ vals, int* __restrict__ col7,
                       float* __restrict__ val7, float* __restrict__ d, int V){
  int v = blockIdx.x*256 + threadIdx.x;
  if (v >= V) return;
  int e0 = rp[v], e1 = rp[v+1];
  float s = 0.f;
  #pragma unroll
  for (int i=0;i<7;i++){
    int e = e0 + i;
    int c  = (e < e1) ? colx[e] : 0;
    float w = (e < e1) ? vals[e] : 0.f;
    col7[v*7+i] = c; val7[v*7+i] = w; s += w;
  }
  d[v] = s;
}

// ---- zero small buffer ----
__global__ void zero_k(float* __restrict__ p, int n){
  int i = blockIdx.x*blockDim.x + threadIdx.x;
  if (i < n) p[i] = 0.f;
}

// ---- fused: s = spmm(x) over C=3, then h1 = relu(s@W1^T + d[v]*b1), bf16 out ----
__global__ void spmm_lin1_k(const float* __restrict__ x, const int* __restrict__ col7,
    const float* __restrict__ val7, const float* __restrict__ d,
    const float* __restrict__ W1, const float* __restrict__ b1,
    unsigned short* __restrict__ out, int V, int R){
  __shared__ float sW[192];
  __shared__ float sB[64];
  int tid = threadIdx.x;
  if (tid < 192) sW[tid] = W1[tid];
  if (tid < 64)  sB[tid] = b1[tid];
  __syncthreads();
  int r = blockIdx.x*256 + tid;
  if (r >= R) return;
  int b = r / V; int v = r - b*V;
  const float* xb = x + (size_t)b*V*3;
  int   cs[7]; float ws[7];
  #pragma unroll
  for (int i=0;i<7;i++){ cs[i] = col7[v*7+i]; ws[i] = val7[v*7+i]; }
  float s0=0.f, s1=0.f, s2=0.f;
  #pragma unroll
  for (int i=0;i<7;i++){
    const float* xr = xb + (size_t)cs[i]*3;
    s0 += ws[i]*xr[0]; s1 += ws[i]*xr[1]; s2 += ws[i]*xr[2];
  }
  float dv = d[v];
  unsigned short* orow = out + (size_t)r*64;
  #pragma unroll
  for (int cg=0; cg<8; ++cg){
    ushort8 o;
    #pragma unroll
    for (int k=0;k<8;k++){
      int c = cg*8 + k;
      float acc = dv*sB[c] + s0*sW[c*3] + s1*sW[c*3+1] + s2*sW[c*3+2];
      o[k] = f2bf(fmaxf(acc, 0.f));
    }
    *reinterpret_cast<ushort8*>(orow + cg*8) = o;
  }
}

// ---- SPMM, fixed-degree-7 unrolled, 8 channels/thread (16B gathers, full MLP) ----
template<int C>
__global__ __launch_bounds__(256) void spmm8_k(const unsigned short* __restrict__ in,
    unsigned short* __restrict__ out, const int* __restrict__ col7,
    const float* __restrict__ val7, int Bn, int V){
  constexpr int CG = C/8;
  int idx = blockIdx.x*256 + threadIdx.x;
  if (idx >= Bn*V*CG) return;
  int cg = idx % CG; int v = (idx/CG) % V; int b = idx/(CG*V);
  const unsigned short* base = in + (size_t)b*V*C + cg*8;
  int cols[7]; float vv[7];
  #pragma unroll
  for (int i=0;i<7;i++){ cols[i] = col7[v*7+i]; vv[i] = val7[v*7+i]; }
  ushort8 g[7];
  #pragma unroll
  for (int i=0;i<7;i++) g[i] = *reinterpret_cast<const ushort8*>(base + (size_t)cols[i]*C);
  float acc[8];
  #pragma unroll
  for (int k=0;k<8;k++) acc[k] = 0.f;
  #pragma unroll
  for (int i=0;i<7;i++){
    float s = vv[i];
    #pragma unroll
    for (int k=0;k<8;k++) acc[k] += s*bf2f(g[i][k]);
  }
  ushort8 o;
  #pragma unroll
  for (int k=0;k<8;k++) o[k] = f2bf(acc[k]);
  *reinterpret_cast<ushort8*>(out + (size_t)idx*8) = o;
}

// ---- MFMA dense linear: out[R,N] = in[R,K](bf16) @ W[N,K]^T + bias*(d[v] or 1), opt ReLU ----
template<int K, int N, bool RELU, bool DBIAS>
__global__ __launch_bounds__(256) void lin_mfma_k(const unsigned short* __restrict__ in,
    const float* __restrict__ W, const float* __restrict__ bias,
    unsigned short* __restrict__ out, int R, const float* __restrict__ dvec, int V){
  constexpr int KP = K + 8;
  constexpr int NF = N / 16;
  constexpr int KS = K / 32;
  __shared__ unsigned short sW[N * KP];
  __shared__ float sB[N];
  int tid = threadIdx.x;
  for (int i = tid*4; i < N*K; i += 1024){
    const float4 wv = *reinterpret_cast<const float4*>(W + i);
    int n = i / K, k = i - n*K;
    unsigned short* dst = &sW[n*KP + k];
    dst[0] = f2bf(wv.x); dst[1] = f2bf(wv.y); dst[2] = f2bf(wv.z); dst[3] = f2bf(wv.w);
  }
  if (tid < N) sB[tid] = bias[tid];
  __syncthreads();

  const int wave = tid >> 6, lane = tid & 63;
  const int l15 = lane & 15, lg = lane >> 4;
  const int rbase = blockIdx.x*128 + wave*32;

  int r0c = min(rbase + l15,      R-1);
  int r1c = min(rbase + 16 + l15, R-1);
  const unsigned short* bp0 = in + (size_t)r0c*K + lg*8;
  const unsigned short* bp1 = in + (size_t)r1c*K + lg*8;
  const unsigned short* aBase = &sW[l15*KP + lg*8];

  f32x4 acc[NF][2];
  #pragma unroll
  for (int nf=0; nf<NF; ++nf){ acc[nf][0] = (f32x4)0.f; acc[nf][1] = (f32x4)0.f; }

  #pragma unroll
  for (int ks=0; ks<KS; ++ks){
    short8v b0 = *reinterpret_cast<const short8v*>(bp0 + ks*32);
    short8v b1 = *reinterpret_cast<const short8v*>(bp1 + ks*32);
    #pragma unroll
    for (int nf=0; nf<NF; ++nf){
      short8v a = *reinterpret_cast<const short8v*>(aBase + nf*16*KP + ks*32);
      acc[nf][0] = __builtin_amdgcn_mfma_f32_16x16x32_bf16(a, b0, acc[nf][0], 0,0,0);
      acc[nf][1] = __builtin_amdgcn_mfma_f32_16x16x32_bf16(a, b1, acc[nf][1], 0,0,0);
    }
  }

  #pragma unroll
  for (int rr=0; rr<2; ++rr){
    int r = rbase + rr*16 + l15;
    if (r >= R) continue;
    float bscale = 1.f;
    if (DBIAS){ int vv = r % V; bscale = dvec[vv]; }
    #pragma unroll
    for (int nf=0; nf<NF; ++nf){
      int nb = nf*16 + lg*4;
      ushort4v o;
      #pragma unroll
      for (int reg=0; reg<4; ++reg){
        float v = acc[nf][rr][reg] + bscale*sB[nb + reg];
        if (RELU) v = v > 0.f ? v : 0.f;
        o[reg] = f2bf(v);
      }
      *reinterpret_cast<ushort4v*>(out + (size_t)r*N + nb) = o;
    }
  }
}

// ---- mean over V: partial sums, atomicAdd into pre-zeroed g[b][128] ----
__global__ void mean_k(const unsigned short* __restrict__ h, float* __restrict__ g, int V){
  int b = blockIdx.x;
  int chunk = blockIdx.y;
  int c = threadIdx.x & 127;
  int s = threadIdx.x >> 7;
  int len = (V + gridDim.y - 1) / gridDim.y;
  int v0 = chunk * len;
  int v1 = min(V, v0 + len);
  float acc = 0.f;
  const unsigned short* base = h + (size_t)b*V*128 + c;
  for (int v = v0 + s; v < v1; v += 2) acc += bf2f(base[(size_t)v*128]);
  __shared__ float red[128];
  if (s == 1) red[c] = acc;
  __syncthreads();
  if (s == 0) atomicAdd(&g[b*128 + c], acc + red[c]);
}

// ---- fused VAE head: one block per batch element ----
// feat = relu(g/V @ Wfc^T + bfc); mu, lv (clipped); z = mu + eps*exp(0.5lv);
// zp[b][c] = bd1[c] + z @ Wd1[c,:32]
__global__ __launch_bounds__(256) void head2_k(const float* __restrict__ g,
    const float* __restrict__ Wfc, const float* __restrict__ bfc,
    const float* __restrict__ Wmu, const float* __restrict__ bmu,
    const float* __restrict__ Wlv, const float* __restrict__ blv,
    const float* __restrict__ eps, const float* __restrict__ Wd1,
    const float* __restrict__ bd1, float* __restrict__ mu_out,
    float* __restrict__ lv_out, float* __restrict__ zp, float invV){
  int b = blockIdx.x;
  int tid = threadIdx.x;
  __shared__ float sG[128];
  __shared__ float sF[256];
  __shared__ float sMu[32];
  __shared__ float sLv[32];
  __shared__ float sZ[32];
  if (tid < 128) sG[tid] = g[b*128 + tid] * invV;
  __syncthreads();
  // feat: one output per thread, float4 weight loads (Wfc L2-resident across blocks)
  {
    const float4* wr = reinterpret_cast<const float4*>(Wfc + tid*128);
    float acc = bfc[tid];
    #pragma unroll 8
    for (int k4=0;k4<32;k4++){
      float4 wv = wr[k4];
      acc += sG[k4*4]*wv.x + sG[k4*4+1]*wv.y + sG[k4*4+2]*wv.z + sG[k4*4+3]*wv.w;
    }
    sF[tid] = fmaxf(acc, 0.f);
  }
  __syncthreads();
  if (tid < 64){
    int c = tid & 31;
    bool isMu = tid < 32;
    const float4* wr = reinterpret_cast<const float4*>((isMu ? Wmu : Wlv) + c*256);
    float acc = isMu ? bmu[c] : blv[c];
    #pragma unroll 8
    for (int k4=0;k4<64;k4++){
      float4 wv = wr[k4];
      acc += sF[k4*4]*wv.x + sF[k4*4+1]*wv.y + sF[k4*4+2]*wv.z + sF[k4*4+3]*wv.w;
    }
    if (isMu){ sMu[c] = acc; mu_out[b*32+c] = acc; }
    else {
      acc = fminf(20.f, fmaxf(-20.f, acc));
      sLv[c] = acc; lv_out[b*32+c] = acc;
    }
  }
  __syncthreads();
  if (tid < 32) sZ[tid] = sMu[tid] + eps[b*32+tid]*expf(0.5f*sLv[tid]);
  __syncthreads();
  if (tid < 128){
    const float* wr = Wd1 + tid*35;
    float acc = bd1[tid];
    #pragma unroll
    for (int k=0;k<32;k++) acc += sZ[k]*wr[k];
    zp[b*128 + tid] = acc;
  }
}

// ---- tpart[v][c] = tmpl[v,:] @ Wd1[c,32:35]  (bf16) ----
__global__ void tpart_k(const float* __restrict__ tmpl, const float* __restrict__ Wd1,
                        unsigned short* __restrict__ tp, int V){
  int o = blockIdx.x*256 + threadIdx.x;
  if (o >= V*128) return;
  int v = o >> 7, c = o & 127;
  const float* wr = Wd1 + c*35 + 32;
  float t = tmpl[v*3]*wr[0] + tmpl[v*3+1]*wr[1] + tmpl[v*3+2]*wr[2];
  tp[o] = f2bf(t);
}

// ---- dec1: hd = relu(zpart[b] + tpart[v]), elementwise, bf16 out ----
__global__ void dec1_elt_k(const float* __restrict__ zp, const unsigned short* __restrict__ tp,
                           unsigned short* __restrict__ out, int V, int R){
  int idx = blockIdx.x*256 + threadIdx.x;
  if (idx >= R*16) return;
  int cg = idx & 15; int r = idx >> 4;
  int b = r / V; int v = r - b*V;
  const float* za = zp + b*128 + cg*8;
  ushort8 t = *reinterpret_cast<const ushort8*>(tp + (size_t)v*128 + cg*8);
  ushort8 o;
  #pragma unroll
  for (int k=0;k<8;k++){
    float val = za[k] + bf2f(t[k]);
    o[k] = f2bf(fmaxf(val, 0.f));
  }
  *reinterpret_cast<ushort8*>(out + (size_t)idx*8) = o;
}

// ---- decoder layer 4: 64 -> 3, + template, fp32 out ----
__global__ void dec4_k(const unsigned short* __restrict__ in, const float* __restrict__ W,
                       const float* __restrict__ b, const float* __restrict__ tmpl,
                       float* __restrict__ out, int V, int R){
  __shared__ float sW[192];
  __shared__ float sB[3];
  int tid = threadIdx.x;
  if (tid < 192) sW[tid] = W[tid];
  if (tid < 3)   sB[tid] = b[tid];
  __syncthreads();
  int r = blockIdx.x*256 + tid;
  if (r >= R) return;
  int v = r % V;
  float a0 = sB[0], a1 = sB[1], a2 = sB[2];
  const unsigned short* hr = in + (size_t)r*64;
  #pragma unroll
  for (int k0 = 0; k0 < 64; k0 += 8){
    ushort8 hv = *reinterpret_cast<const ushort8*>(hr + k0);
    #pragma unroll
    for (int kk=0;kk<8;kk++){
      float h = bf2f(hv[kk]);
      a0 += h*sW[0*64 + k0+kk];
      a1 += h*sW[1*64 + k0+kk];
      a2 += h*sW[2*64 + k0+kk];
    }
  }
  out[(size_t)r*3+0] = tmpl[v*3+0] + a0;
  out[(size_t)r*3+1] = tmpl[v*3+1] + a1;
  out[(size_t)r*3+2] = tmpl[v*3+2] + a2;
}

extern "C" void kernel_launch(void* const* d_in, const int* in_sizes, int n_in,
                              void* d_out, int out_size, void* d_ws, size_t ws_size,
                              hipStream_t stream){
  const float* x    = (const float*)d_in[0];
  const float* eps  = (const float*)d_in[1];
  const int*   row  = (const int*)d_in[2];
  const int*   colx = (const int*)d_in[3];
  const float* vals = (const float*)d_in[4];
  const float* tmpl = (const float*)d_in[5];
  const float* W1 = (const float*)d_in[6];  const float* b1 = (const float*)d_in[7];
  const float* W2 = (const float*)d_in[8];  const float* b2 = (const float*)d_in[9];
  const float* W3 = (const float*)d_in[10]; const float* b3 = (const float*)d_in[11];
  const float* Wfc= (const float*)d_in[12]; const float* bfc= (const float*)d_in[13];
  const float* Wmu= (const float*)d_in[14]; const float* bmu= (const float*)d_in[15];
  const float* Wlv= (const float*)d_in[16]; const float* blv= (const float*)d_in[17];
  const float* Wd1= (const float*)d_in[18]; const float* bd1= (const float*)d_in[19];
  const float* Wd2= (const float*)d_in[20]; const float* bd2= (const float*)d_in[21];
  const float* Wd3= (const float*)d_in[22]; const float* bd3= (const float*)d_in[23];
  const float* Wd4= (const float*)d_in[24]; const float* bd4= (const float*)d_in[25];

  int V   = in_sizes[5] / 3;     // 10242
  int Bn  = in_sizes[1] / 32;    // 16
  int nnz = in_sizes[2];         // 71682
  int R   = Bn * V;              // 163872

  // workspace layout
  char* w = (char*)d_ws;
  size_t off = 0;
  auto alloc = [&](size_t bytes)->char*{
    char* p = w + off; off = (off + bytes + 255) & ~(size_t)255; return p;
  };
  size_t bufBytes = (size_t)R * 128 * sizeof(unsigned short);
  unsigned short* bufA = (unsigned short*)alloc(bufBytes);
  unsigned short* bufB = (unsigned short*)alloc(bufBytes);
  int*   rp   = (int*)alloc((size_t)(V+1)*4);
  int*   col7 = (int*)alloc((size_t)V*7*4);
  float* val7 = (float*)alloc((size_t)V*7*4);
  float* dvec = (float*)alloc((size_t)V*4);
  float* g    = (float*)alloc((size_t)Bn*128*4);
  float* zp   = (float*)alloc((size_t)Bn*128*4);
  unsigned short* tp = (unsigned short*)alloc((size_t)V*128*2);

  float* recon  = (float*)d_out;
  float* mu_out = recon + (size_t)R*3;
  float* lv_out = mu_out + (size_t)Bn*32;

  int mfmaGrid = (R + 127) / 128;

  // graph prep
  rowptr_k<<<(V+1+255)/256, 256, 0, stream>>>(row, nnz, rp, V);
  pad7_k<<<(V+255)/256, 256, 0, stream>>>(rp, colx, vals, col7, val7, dvec, V);

  // encoder (spmm/linear reordered: lin(spmm(h)) with d-scaled bias)
  spmm_lin1_k<<<(R+255)/256, 256, 0, stream>>>(x, col7, val7, dvec, W1, b1, bufA, V, R);
  spmm8_k<64><<<(R*8+255)/256, 256, 0, stream>>>(bufA, bufB, col7, val7, Bn, V);
  lin_mfma_k<64,64,true,true><<<mfmaGrid, 256, 0, stream>>>(bufB, W2, b2, bufA, R, dvec, V);
  spmm8_k<64><<<(R*8+255)/256, 256, 0, stream>>>(bufA, bufB, col7, val7, Bn, V);
  lin_mfma_k<64,128,true,true><<<mfmaGrid, 256, 0, stream>>>(bufB, W3, b3, bufA, R, dvec, V);

  // pool + fused head (feat/mu/lv/z/zpart)
  zero_k<<<(Bn*128+255)/256, 256, 0, stream>>>(g, Bn*128);
  mean_k<<<dim3(Bn, 32), 256, 0, stream>>>(bufA, g, V);
  head2_k<<<Bn, 256, 0, stream>>>(g, Wfc, bfc, Wmu, bmu, Wlv, blv, eps, Wd1, bd1,
                                  mu_out, lv_out, zp, 1.0f/(float)V);

  // decoder
  tpart_k<<<(V*128+255)/256, 256, 0, stream>>>(tmpl, Wd1, tp, V);
  dec1_elt_k<<<(R*16+255)/256, 256, 0, stream>>>(zp, tp, bufB, V, R);
  lin_mfma_k<128,128,true,false><<<mfmaGrid, 256, 0, stream>>>(bufB, Wd2, bd2, bufA, R, nullptr, V);
  lin_mfma_k<128,64,true,false><<<mfmaGrid, 256, 0, stream>>>(bufA, Wd3, bd3, bufB, R, nullptr, V);
  dec4_k<<<(R+255)/256, 256, 0, stream>>>(bufB, Wd4, bd4, tmpl, recon, V, R);
}

// Round 5
// 164.988 us; speedup vs baseline: 52.1425x; 1.3340x over previous
//
#include <hip/hip_runtime.h>
#include <hip/hip_bf16.h>

typedef __attribute__((ext_vector_type(8))) unsigned short ushort8;
typedef __attribute__((ext_vector_type(4))) unsigned short ushort4v;
typedef __attribute__((ext_vector_type(8))) short short8v;
typedef __attribute__((ext_vector_type(4))) float f32x4;

__device__ __forceinline__ float bf2f(unsigned short u){
  union { unsigned int i; float f; } x; x.i = ((unsigned int)u) << 16; return x.f;
}
__device__ __forceinline__ unsigned short f2bf(float f){
  __hip_bfloat16 h = __float2bfloat16(f);
  return *reinterpret_cast<unsigned short*>(&h);
}

// ---- CSR row_ptr via binary search over sorted row[] ----
__global__ void rowptr_k(const int* __restrict__ row, int nnz, int* __restrict__ rp, int V){
  int v = blockIdx.x*blockDim.x + threadIdx.x;
  if (v > V) return;
  int lo = 0, hi = nnz;
  while (lo < hi){ int m = (lo+hi)>>1; if (row[m] < v) lo = m+1; else hi = m; }
  rp[v] = lo;
}

// ---- pad edges to fixed degree 7, rowsum d ----
__global__ void pad7_k(const int* __restrict__ rp, const int* __restrict__ colx,
                       const float* __restrict__ vals, int* __restrict__ col7,
                       float* __restrict__ val7, float* __restrict__ d, int V){
  int v = blockIdx.x*256 + threadIdx.x;
  if (v >= V) return;
  int e0 = rp[v], e1 = rp[v+1];
  float s = 0.f;
  #pragma unroll
  for (int i=0;i<7;i++){
    int e = e0 + i;
    int c  = (e < e1) ? colx[e] : 0;
    float w = (e < e1) ? vals[e] : 0.f;
    col7[v*7+i] = c; val7[v*7+i] = w; s += w;
  }
  d[v] = s;
}

__global__ void zero_k(float* __restrict__ p, int n){
  int i = blockIdx.x*blockDim.x + threadIdx.x;
  if (i < n) p[i] = 0.f;
}

// ---- fused: s = spmm(x) over C=3, then h1 = relu(s@W1^T + d[v]*b1), bf16 out ----
__global__ void spmm_lin1_k(const float* __restrict__ x, const int* __restrict__ col7,
    const float* __restrict__ val7, const float* __restrict__ d,
    const float* __restrict__ W1, const float* __restrict__ b1,
    unsigned short* __restrict__ out, int V, int R){
  __shared__ float sW[192];
  __shared__ float sB[64];
  int tid = threadIdx.x;
  if (tid < 192) sW[tid] = W1[tid];
  if (tid < 64)  sB[tid] = b1[tid];
  __syncthreads();
  int r = blockIdx.x*256 + tid;
  if (r >= R) return;
  int b = r / V; int v = r - b*V;
  const float* xb = x + (size_t)b*V*3;
  int   cs[7]; float ws[7];
  #pragma unroll
  for (int i=0;i<7;i++){ cs[i] = col7[v*7+i]; ws[i] = val7[v*7+i]; }
  float s0=0.f, s1=0.f, s2=0.f;
  #pragma unroll
  for (int i=0;i<7;i++){
    const float* xr = xb + (size_t)cs[i]*3;
    s0 += ws[i]*xr[0]; s1 += ws[i]*xr[1]; s2 += ws[i]*xr[2];
  }
  float dv = d[v];
  unsigned short* orow = out + (size_t)r*64;
  #pragma unroll
  for (int cg=0; cg<8; ++cg){
    ushort8 o;
    #pragma unroll
    for (int k=0;k<8;k++){
      int c = cg*8 + k;
      float acc = dv*sB[c] + s0*sW[c*3] + s1*sW[c*3+1] + s2*sW[c*3+2];
      o[k] = f2bf(fmaxf(acc, 0.f));
    }
    *reinterpret_cast<ushort8*>(orow + cg*8) = o;
  }
}

// ---- SPMM, fixed-degree-7 unrolled, 8 channels/thread ----
template<int C>
__global__ __launch_bounds__(256) void spmm8_k(const unsigned short* __restrict__ in,
    unsigned short* __restrict__ out, const int* __restrict__ col7,
    const float* __restrict__ val7, int Bn, int V){
  constexpr int CG = C/8;
  int idx = blockIdx.x*256 + threadIdx.x;
  if (idx >= Bn*V*CG) return;
  int cg = idx % CG; int v = (idx/CG) % V; int b = idx/(CG*V);
  const unsigned short* base = in + (size_t)b*V*C + cg*8;
  int cols[7]; float vv[7];
  #pragma unroll
  for (int i=0;i<7;i++){ cols[i] = col7[v*7+i]; vv[i] = val7[v*7+i]; }
  ushort8 g[7];
  #pragma unroll
  for (int i=0;i<7;i++) g[i] = *reinterpret_cast<const ushort8*>(base + (size_t)cols[i]*C);
  float acc[8];
  #pragma unroll
  for (int k=0;k<8;k++) acc[k] = 0.f;
  #pragma unroll
  for (int i=0;i<7;i++){
    float s = vv[i];
    #pragma unroll
    for (int k=0;k<8;k++) acc[k] += s*bf2f(g[i][k]);
  }
  ushort8 o;
  #pragma unroll
  for (int k=0;k<8;k++) o[k] = f2bf(acc[k]);
  *reinterpret_cast<ushort8*>(out + (size_t)idx*8) = o;
}

// ---- MFMA dense linear (generic, with store): out = relu(in@W^T + bscale*b) ----
template<int K, int N, bool RELU, bool DBIAS>
__global__ __launch_bounds__(256) void lin_mfma_k(const unsigned short* __restrict__ in,
    const float* __restrict__ W, const float* __restrict__ bias,
    unsigned short* __restrict__ out, int R, const float* __restrict__ dvec, int V){
  constexpr int KP = K + 8;
  constexpr int NF = N / 16;
  constexpr int KS = K / 32;
  __shared__ unsigned short sW[N * KP];
  __shared__ float sB[N];
  int tid = threadIdx.x;
  for (int i = tid*4; i < N*K; i += 1024){
    const float4 wv = *reinterpret_cast<const float4*>(W + i);
    int n = i / K, k = i - n*K;
    unsigned short* dst = &sW[n*KP + k];
    dst[0] = f2bf(wv.x); dst[1] = f2bf(wv.y); dst[2] = f2bf(wv.z); dst[3] = f2bf(wv.w);
  }
  if (tid < N) sB[tid] = bias[tid];
  __syncthreads();

  const int wave = tid >> 6, lane = tid & 63;
  const int l15 = lane & 15, lg = lane >> 4;
  const int rbase = blockIdx.x*128 + wave*32;

  int r0c = min(rbase + l15,      R-1);
  int r1c = min(rbase + 16 + l15, R-1);
  const unsigned short* bp0 = in + (size_t)r0c*K + lg*8;
  const unsigned short* bp1 = in + (size_t)r1c*K + lg*8;
  const unsigned short* aBase = &sW[l15*KP + lg*8];

  f32x4 acc[NF][2];
  #pragma unroll
  for (int nf=0; nf<NF; ++nf){ acc[nf][0] = (f32x4)0.f; acc[nf][1] = (f32x4)0.f; }

  #pragma unroll
  for (int ks=0; ks<KS; ++ks){
    short8v b0 = *reinterpret_cast<const short8v*>(bp0 + ks*32);
    short8v b1 = *reinterpret_cast<const short8v*>(bp1 + ks*32);
    #pragma unroll
    for (int nf=0; nf<NF; ++nf){
      short8v a = *reinterpret_cast<const short8v*>(aBase + nf*16*KP + ks*32);
      acc[nf][0] = __builtin_amdgcn_mfma_f32_16x16x32_bf16(a, b0, acc[nf][0], 0,0,0);
      acc[nf][1] = __builtin_amdgcn_mfma_f32_16x16x32_bf16(a, b1, acc[nf][1], 0,0,0);
    }
  }

  #pragma unroll
  for (int rr=0; rr<2; ++rr){
    int r = rbase + rr*16 + l15;
    if (r >= R) continue;
    float bscale = 1.f;
    if (DBIAS){ int vv = r % V; bscale = dvec[vv]; }
    #pragma unroll
    for (int nf=0; nf<NF; ++nf){
      int nb = nf*16 + lg*4;
      ushort4v o;
      #pragma unroll
      for (int reg=0; reg<4; ++reg){
        float v = acc[nf][rr][reg] + bscale*sB[nb + reg];
        if (RELU) v = v > 0.f ? v : 0.f;
        o[reg] = f2bf(v);
      }
      *reinterpret_cast<ushort4v*>(out + (size_t)r*N + nb) = o;
    }
  }
}

// ---- layer-3 linear + relu + mean-pool, NO global store of h3 ----
// h3[r,c] = relu(in[r]@W^T + d[v]*b); g[b][c] += sum_v h3   (atomic, fp32)
__global__ __launch_bounds__(256) void lin3_mean_k(const unsigned short* __restrict__ in,
    const float* __restrict__ W, const float* __restrict__ bias,
    const float* __restrict__ dvec, float* __restrict__ g, int R, int V, int Bn){
  constexpr int K = 64, N = 128, KP = K + 8, NF = N/16, KS = K/32;
  __shared__ unsigned short sW[N * KP];
  __shared__ float sB[N];
  __shared__ float gPart[2][128];
  int tid = threadIdx.x;
  for (int i = tid*4; i < N*K; i += 1024){
    const float4 wv = *reinterpret_cast<const float4*>(W + i);
    int n = i / K, k = i - n*K;
    unsigned short* dst = &sW[n*KP + k];
    dst[0] = f2bf(wv.x); dst[1] = f2bf(wv.y); dst[2] = f2bf(wv.z); dst[3] = f2bf(wv.w);
  }
  if (tid < N) sB[tid] = bias[tid];
  if (tid < 128){ gPart[0][tid] = 0.f; gPart[1][tid] = 0.f; }
  __syncthreads();

  const int wave = tid >> 6, lane = tid & 63;
  const int l15 = lane & 15, lg = lane >> 4;
  const int rbase = blockIdx.x*128 + wave*32;

  int r0 = rbase + l15;        // actual (unclamped) rows
  int r1 = rbase + 16 + l15;
  int r0c = min(r0, R-1), r1c = min(r1, R-1);
  const unsigned short* bp0 = in + (size_t)r0c*K + lg*8;
  const unsigned short* bp1 = in + (size_t)r1c*K + lg*8;
  const unsigned short* aBase = &sW[l15*KP + lg*8];

  f32x4 acc[NF][2];
  #pragma unroll
  for (int nf=0; nf<NF; ++nf){ acc[nf][0] = (f32x4)0.f; acc[nf][1] = (f32x4)0.f; }

  #pragma unroll
  for (int ks=0; ks<KS; ++ks){
    short8v b0 = *reinterpret_cast<const short8v*>(bp0 + ks*32);
    short8v b1 = *reinterpret_cast<const short8v*>(bp1 + ks*32);
    #pragma unroll
    for (int nf=0; nf<NF; ++nf){
      short8v a = *reinterpret_cast<const short8v*>(aBase + nf*16*KP + ks*32);
      acc[nf][0] = __builtin_amdgcn_mfma_f32_16x16x32_bf16(a, b0, acc[nf][0], 0,0,0);
      acc[nf][1] = __builtin_amdgcn_mfma_f32_16x16x32_bf16(a, b1, acc[nf][1], 0,0,0);
    }
  }

  // epilogue: relu + masked per-batch-bucket reduce over the 16 row-lanes
  const int b0blk = (blockIdx.x*128) / V;
  bool ok0 = r0 < R, ok1 = r1 < R;
  int bb0 = r0c / V, bb1 = r1c / V;
  float d0 = dvec[r0c - bb0*V], d1 = dvec[r1c - bb1*V];
  bool in00 = ok0 && (bb0 == b0blk), in01 = ok0 && (bb0 == b0blk+1);
  bool in10 = ok1 && (bb1 == b0blk), in11 = ok1 && (bb1 == b0blk+1);

  #pragma unroll
  for (int nf=0; nf<NF; ++nf){
    #pragma unroll
    for (int reg=0; reg<4; ++reg){
      int c = nf*16 + lg*4 + reg;
      float v0 = fmaxf(acc[nf][0][reg] + d0*sB[c], 0.f);
      float v1 = fmaxf(acc[nf][1][reg] + d1*sB[c], 0.f);
      float sA = (in00 ? v0 : 0.f) + (in10 ? v1 : 0.f);
      float sBv= (in01 ? v0 : 0.f) + (in11 ? v1 : 0.f);
      #pragma unroll
      for (int m=1; m<16; m<<=1){
        sA  += __shfl_xor(sA,  m);
        sBv += __shfl_xor(sBv, m);
      }
      if (l15 == 0){
        atomicAdd(&gPart[0][c], sA);
        atomicAdd(&gPart[1][c], sBv);
      }
    }
  }
  __syncthreads();
  if (tid < 128){
    float a = gPart[0][tid];
    if (a != 0.f) atomicAdd(&g[b0blk*128 + tid], a);
    float b2 = gPart[1][tid];
    if (b2 != 0.f && b0blk+1 < Bn) atomicAdd(&g[(b0blk+1)*128 + tid], b2);
  }
}

// ---- fused VAE head: one block per batch element ----
__global__ __launch_bounds__(256) void head2_k(const float* __restrict__ g,
    const float* __restrict__ Wfc, const float* __restrict__ bfc,
    const float* __restrict__ Wmu, const float* __restrict__ bmu,
    const float* __restrict__ Wlv, const float* __restrict__ blv,
    const float* __restrict__ eps, const float* __restrict__ Wd1,
    const float* __restrict__ bd1, float* __restrict__ mu_out,
    float* __restrict__ lv_out, float* __restrict__ zp, float invV){
  int b = blockIdx.x;
  int tid = threadIdx.x;
  __shared__ float sG[128];
  __shared__ float sF[256];
  __shared__ float sMu[32];
  __shared__ float sLv[32];
  __shared__ float sZ[32];
  if (tid < 128) sG[tid] = g[b*128 + tid] * invV;
  __syncthreads();
  {
    const float4* wr = reinterpret_cast<const float4*>(Wfc + tid*128);
    float acc = bfc[tid];
    #pragma unroll 8
    for (int k4=0;k4<32;k4++){
      float4 wv = wr[k4];
      acc += sG[k4*4]*wv.x + sG[k4*4+1]*wv.y + sG[k4*4+2]*wv.z + sG[k4*4+3]*wv.w;
    }
    sF[tid] = fmaxf(acc, 0.f);
  }
  __syncthreads();
  if (tid < 64){
    int c = tid & 31;
    bool isMu = tid < 32;
    const float4* wr = reinterpret_cast<const float4*>((isMu ? Wmu : Wlv) + c*256);
    float acc = isMu ? bmu[c] : blv[c];
    #pragma unroll 8
    for (int k4=0;k4<64;k4++){
      float4 wv = wr[k4];
      acc += sF[k4*4]*wv.x + sF[k4*4+1]*wv.y + sF[k4*4+2]*wv.z + sF[k4*4+3]*wv.w;
    }
    if (isMu){ sMu[c] = acc; mu_out[b*32+c] = acc; }
    else {
      acc = fminf(20.f, fmaxf(-20.f, acc));
      sLv[c] = acc; lv_out[b*32+c] = acc;
    }
  }
  __syncthreads();
  if (tid < 32) sZ[tid] = sMu[tid] + eps[b*32+tid]*expf(0.5f*sLv[tid]);
  __syncthreads();
  if (tid < 128){
    const float* wr = Wd1 + tid*35;
    float acc = bd1[tid];
    #pragma unroll
    for (int k=0;k<32;k++) acc += sZ[k]*wr[k];
    zp[b*128 + tid] = acc;
  }
}

// ---- tpart[v][c] = tmpl[v,:] @ Wd1[c,32:35]  (bf16) ----
__global__ void tpart_k(const float* __restrict__ tmpl, const float* __restrict__ Wd1,
                        unsigned short* __restrict__ tp, int V){
  int o = blockIdx.x*256 + threadIdx.x;
  if (o >= V*128) return;
  int v = o >> 7, c = o & 127;
  const float* wr = Wd1 + c*35 + 32;
  float t = tmpl[v*3]*wr[0] + tmpl[v*3+1]*wr[1] + tmpl[v*3+2]*wr[2];
  tp[o] = f2bf(t);
}

// ---- decoder layer 2 with on-the-fly B: hd1 = relu(zp[b]+tp[v]); out = relu(hd1@Wd2^T+bd2) ----
__global__ __launch_bounds__(256) void lin_dec2_k(const float* __restrict__ zp,
    const unsigned short* __restrict__ tp, const float* __restrict__ W,
    const float* __restrict__ bias, unsigned short* __restrict__ out, int R, int V){
  constexpr int K = 128, N = 128, KP = K + 8, NF = N/16, KS = K/32;
  __shared__ unsigned short sW[N * KP];
  __shared__ float sB[N];
  int tid = threadIdx.x;
  for (int i = tid*4; i < N*K; i += 1024){
    const float4 wv = *reinterpret_cast<const float4*>(W + i);
    int n = i / K, k = i - n*K;
    unsigned short* dst = &sW[n*KP + k];
    dst[0] = f2bf(wv.x); dst[1] = f2bf(wv.y); dst[2] = f2bf(wv.z); dst[3] = f2bf(wv.w);
  }
  if (tid < N) sB[tid] = bias[tid];
  __syncthreads();

  const int wave = tid >> 6, lane = tid & 63;
  const int l15 = lane & 15, lg = lane >> 4;
  const int rbase = blockIdx.x*128 + wave*32;

  int r0c = min(rbase + l15,      R-1);
  int r1c = min(rbase + 16 + l15, R-1);
  int b0i = r0c / V, v0i = r0c - b0i*V;
  int b1i = r1c / V, v1i = r1c - b1i*V;
  const float* zp0 = zp + b0i*128 + lg*8;
  const float* zp1 = zp + b1i*128 + lg*8;
  const unsigned short* tp0 = tp + (size_t)v0i*128 + lg*8;
  const unsigned short* tp1 = tp + (size_t)v1i*128 + lg*8;
  const unsigned short* aBase = &sW[l15*KP + lg*8];

  f32x4 acc[NF][2];
  #pragma unroll
  for (int nf=0; nf<NF; ++nf){ acc[nf][0] = (f32x4)0.f; acc[nf][1] = (f32x4)0.f; }

  #pragma unroll
  for (int ks=0; ks<KS; ++ks){
    float4 za0 = *reinterpret_cast<const float4*>(zp0 + ks*32);
    float4 zb0 = *reinterpret_cast<const float4*>(zp0 + ks*32 + 4);
    float4 za1 = *reinterpret_cast<const float4*>(zp1 + ks*32);
    float4 zb1 = *reinterpret_cast<const float4*>(zp1 + ks*32 + 4);
    ushort8 t0 = *reinterpret_cast<const ushort8*>(tp0 + ks*32);
    ushort8 t1 = *reinterpret_cast<const ushort8*>(tp1 + ks*32);
    short8v b0, b1;
    b0[0]=(short)f2bf(fmaxf(za0.x+bf2f(t0[0]),0.f)); b0[1]=(short)f2bf(fmaxf(za0.y+bf2f(t0[1]),0.f));
    b0[2]=(short)f2bf(fmaxf(za0.z+bf2f(t0[2]),0.f)); b0[3]=(short)f2bf(fmaxf(za0.w+bf2f(t0[3]),0.f));
    b0[4]=(short)f2bf(fmaxf(zb0.x+bf2f(t0[4]),0.f)); b0[5]=(short)f2bf(fmaxf(zb0.y+bf2f(t0[5]),0.f));
    b0[6]=(short)f2bf(fmaxf(zb0.z+bf2f(t0[6]),0.f)); b0[7]=(short)f2bf(fmaxf(zb0.w+bf2f(t0[7]),0.f));
    b1[0]=(short)f2bf(fmaxf(za1.x+bf2f(t1[0]),0.f)); b1[1]=(short)f2bf(fmaxf(za1.y+bf2f(t1[1]),0.f));
    b1[2]=(short)f2bf(fmaxf(za1.z+bf2f(t1[2]),0.f)); b1[3]=(short)f2bf(fmaxf(za1.w+bf2f(t1[3]),0.f));
    b1[4]=(short)f2bf(fmaxf(zb1.x+bf2f(t1[4]),0.f)); b1[5]=(short)f2bf(fmaxf(zb1.y+bf2f(t1[5]),0.f));
    b1[6]=(short)f2bf(fmaxf(zb1.z+bf2f(t1[6]),0.f)); b1[7]=(short)f2bf(fmaxf(zb1.w+bf2f(t1[7]),0.f));
    #pragma unroll
    for (int nf=0; nf<NF; ++nf){
      short8v a = *reinterpret_cast<const short8v*>(aBase + nf*16*KP + ks*32);
      acc[nf][0] = __builtin_amdgcn_mfma_f32_16x16x32_bf16(a, b0, acc[nf][0], 0,0,0);
      acc[nf][1] = __builtin_amdgcn_mfma_f32_16x16x32_bf16(a, b1, acc[nf][1], 0,0,0);
    }
  }

  #pragma unroll
  for (int rr=0; rr<2; ++rr){
    int r = rbase + rr*16 + l15;
    if (r >= R) continue;
    #pragma unroll
    for (int nf=0; nf<NF; ++nf){
      int nb = nf*16 + lg*4;
      ushort4v o;
      #pragma unroll
      for (int reg=0; reg<4; ++reg){
        float v = fmaxf(acc[nf][rr][reg] + sB[nb + reg], 0.f);
        o[reg] = f2bf(v);
      }
      *reinterpret_cast<ushort4v*>(out + (size_t)r*N + nb) = o;
    }
  }
}

// ---- decoder layers 3+4 fused: h4 = relu(in@Wd3^T+bd3); recon = tmpl + h4@Wd4^T+bd4 ----
__global__ __launch_bounds__(256) void lin_dec34_k(const unsigned short* __restrict__ in,
    const float* __restrict__ W3, const float* __restrict__ b3,
    const float* __restrict__ W4, const float* __restrict__ b4,
    const float* __restrict__ tmpl, float* __restrict__ out, int R, int V){
  constexpr int K = 128, N = 64, KP = K + 8, NF = N/16, KS = K/32;
  __shared__ unsigned short sW[N * KP];
  __shared__ float sB3[N];
  __shared__ float sW4[3*64];
  int tid = threadIdx.x;
  for (int i = tid*4; i < N*K; i += 1024){
    const float4 wv = *reinterpret_cast<const float4*>(W3 + i);
    int n = i / K, k = i - n*K;
    unsigned short* dst = &sW[n*KP + k];
    dst[0] = f2bf(wv.x); dst[1] = f2bf(wv.y); dst[2] = f2bf(wv.z); dst[3] = f2bf(wv.w);
  }
  if (tid < N) sB3[tid] = b3[tid];
  if (tid < 192) sW4[tid] = W4[tid];
  __syncthreads();

  const int wave = tid >> 6, lane = tid & 63;
  const int l15 = lane & 15, lg = lane >> 4;
  const int rbase = blockIdx.x*128 + wave*32;

  int r0c = min(rbase + l15,      R-1);
  int r1c = min(rbase + 16 + l15, R-1);
  const unsigned short* bp0 = in + (size_t)r0c*K + lg*8;
  const unsigned short* bp1 = in + (size_t)r1c*K + lg*8;
  const unsigned short* aBase = &sW[l15*KP + lg*8];

  f32x4 acc[NF][2];
  #pragma unroll
  for (int nf=0; nf<NF; ++nf){ acc[nf][0] = (f32x4)0.f; acc[nf][1] = (f32x4)0.f; }

  #pragma unroll
  for (int ks=0; ks<KS; ++ks){
    short8v b0 = *reinterpret_cast<const short8v*>(bp0 + ks*32);
    short8v b1 = *reinterpret_cast<const short8v*>(bp1 + ks*32);
    #pragma unroll
    for (int nf=0; nf<NF; ++nf){
      short8v a = *reinterpret_cast<const short8v*>(aBase + nf*16*KP + ks*32);
      acc[nf][0] = __builtin_amdgcn_mfma_f32_16x16x32_bf16(a, b0, acc[nf][0], 0,0,0);
      acc[nf][1] = __builtin_amdgcn_mfma_f32_16x16x32_bf16(a, b1, acc[nf][1], 0,0,0);
    }
  }

  // fused 64->3 projection: per-lane partials over its 16 channels, reduce over lg lanes
  #pragma unroll
  for (int rr=0; rr<2; ++rr){
    int r = rbase + rr*16 + l15;
    float p0 = 0.f, p1 = 0.f, p2 = 0.f;
    #pragma unroll
    for (int nf=0; nf<NF; ++nf){
      #pragma unroll
      for (int reg=0; reg<4; ++reg){
        int c = nf*16 + lg*4 + reg;
        float h = fmaxf(acc[nf][rr][reg] + sB3[c], 0.f);
        p0 += h*sW4[c]; p1 += h*sW4[64+c]; p2 += h*sW4[128+c];
      }
    }
    p0 += __shfl_xor(p0,16); p0 += __shfl_xor(p0,32);
    p1 += __shfl_xor(p1,16); p1 += __shfl_xor(p1,32);
    p2 += __shfl_xor(p2,16); p2 += __shfl_xor(p2,32);
    if (lg == 0 && r < R){
      int v = r % V;
      out[(size_t)r*3+0] = tmpl[v*3+0] + p0 + b4[0];
      out[(size_t)r*3+1] = tmpl[v*3+1] + p1 + b4[1];
      out[(size_t)r*3+2] = tmpl[v*3+2] + p2 + b4[2];
    }
  }
}

extern "C" void kernel_launch(void* const* d_in, const int* in_sizes, int n_in,
                              void* d_out, int out_size, void* d_ws, size_t ws_size,
                              hipStream_t stream){
  const float* x    = (const float*)d_in[0];
  const float* eps  = (const float*)d_in[1];
  const int*   row  = (const int*)d_in[2];
  const int*   colx = (const int*)d_in[3];
  const float* vals = (const float*)d_in[4];
  const float* tmpl = (const float*)d_in[5];
  const float* W1 = (const float*)d_in[6];  const float* b1 = (const float*)d_in[7];
  const float* W2 = (const float*)d_in[8];  const float* b2 = (const float*)d_in[9];
  const float* W3 = (const float*)d_in[10]; const float* b3 = (const float*)d_in[11];
  const float* Wfc= (const float*)d_in[12]; const float* bfc= (const float*)d_in[13];
  const float* Wmu= (const float*)d_in[14]; const float* bmu= (const float*)d_in[15];
  const float* Wlv= (const float*)d_in[16]; const float* blv= (const float*)d_in[17];
  const float* Wd1= (const float*)d_in[18]; const float* bd1= (const float*)d_in[19];
  const float* Wd2= (const float*)d_in[20]; const float* bd2= (const float*)d_in[21];
  const float* Wd3= (const float*)d_in[22]; const float* bd3= (const float*)d_in[23];
  const float* Wd4= (const float*)d_in[24]; const float* bd4= (const float*)d_in[25];

  int V   = in_sizes[5] / 3;     // 10242
  int Bn  = in_sizes[1] / 32;    // 16
  int nnz = in_sizes[2];         // 71682
  int R   = Bn * V;              // 163872

  // workspace layout
  char* w = (char*)d_ws;
  size_t off = 0;
  auto alloc = [&](size_t bytes)->char*{
    char* p = w + off; off = (off + bytes + 255) & ~(size_t)255; return p;
  };
  size_t bufBytes = (size_t)R * 128 * sizeof(unsigned short);
  unsigned short* bufA = (unsigned short*)alloc(bufBytes);
  unsigned short* bufB = (unsigned short*)alloc(bufBytes);
  int*   rp   = (int*)alloc((size_t)(V+1)*4);
  int*   col7 = (int*)alloc((size_t)V*7*4);
  float* val7 = (float*)alloc((size_t)V*7*4);
  float* dvec = (float*)alloc((size_t)V*4);
  float* g    = (float*)alloc((size_t)Bn*128*4);
  float* zp   = (float*)alloc((size_t)Bn*128*4);
  unsigned short* tp = (unsigned short*)alloc((size_t)V*128*2);

  float* recon  = (float*)d_out;
  float* mu_out = recon + (size_t)R*3;
  float* lv_out = mu_out + (size_t)Bn*32;

  int mfmaGrid = (R + 127) / 128;

  // graph prep
  rowptr_k<<<(V+1+255)/256, 256, 0, stream>>>(row, nnz, rp, V);
  pad7_k<<<(V+255)/256, 256, 0, stream>>>(rp, colx, vals, col7, val7, dvec, V);
  zero_k<<<(Bn*128+255)/256, 256, 0, stream>>>(g, Bn*128);

  // encoder (spmm/linear reordered: lin(spmm(h)) with d-scaled bias)
  spmm_lin1_k<<<(R+255)/256, 256, 0, stream>>>(x, col7, val7, dvec, W1, b1, bufA, V, R);
  spmm8_k<64><<<(R*8+255)/256, 256, 0, stream>>>(bufA, bufB, col7, val7, Bn, V);
  lin_mfma_k<64,64,true,true><<<mfmaGrid, 256, 0, stream>>>(bufB, W2, b2, bufA, R, dvec, V);
  spmm8_k<64><<<(R*8+255)/256, 256, 0, stream>>>(bufA, bufB, col7, val7, Bn, V);
  lin3_mean_k<<<mfmaGrid, 256, 0, stream>>>(bufB, W3, b3, dvec, g, R, V, Bn);

  // head (feat/mu/lv/z/zpart)
  head2_k<<<Bn, 256, 0, stream>>>(g, Wfc, bfc, Wmu, bmu, Wlv, blv, eps, Wd1, bd1,
                                  mu_out, lv_out, zp, 1.0f/(float)V);

  // decoder
  tpart_k<<<(V*128+255)/256, 256, 0, stream>>>(tmpl, Wd1, tp, V);
  lin_dec2_k<<<mfmaGrid, 256, 0, stream>>>(zp, tp, Wd2, bd2, bufA, R, V);
  lin_dec34_k<<<mfmaGrid, 256, 0, stream>>>(bufA, Wd3, bd3, Wd4, bd4, tmpl, recon, R, V);
}

// Round 6
// 163.344 us; speedup vs baseline: 52.6671x; 1.0101x over previous
//
#include <hip/hip_runtime.h>
#include <hip/hip_bf16.h>

typedef __attribute__((ext_vector_type(8))) unsigned short ushort8;
typedef __attribute__((ext_vector_type(4))) unsigned short ushort4v;
typedef __attribute__((ext_vector_type(8))) short short8v;
typedef __attribute__((ext_vector_type(4))) float f32x4;

__device__ __forceinline__ float bf2f(unsigned short u){
  union { unsigned int i; float f; } x; x.i = ((unsigned int)u) << 16; return x.f;
}
__device__ __forceinline__ unsigned short f2bf(float f){
  __hip_bfloat16 h = __float2bfloat16(f);
  return *reinterpret_cast<unsigned short*>(&h);
}

// ---- prep: col7/val7/dvec via two binary searches over sorted row[]; zero g ----
__global__ void prep_k(const int* __restrict__ row, const int* __restrict__ colx,
                       const float* __restrict__ vals, int nnz,
                       int* __restrict__ col7, float* __restrict__ val7,
                       float* __restrict__ dvec, float* __restrict__ g, int V, int GN){
  int v = blockIdx.x*256 + threadIdx.x;
  if (v < GN) g[v] = 0.f;
  if (v >= V) return;
  int lo = 0, hi = nnz;
  while (lo < hi){ int m = (lo+hi)>>1; if (row[m] < v) lo = m+1; else hi = m; }
  int e0 = lo;
  int lo2 = e0; hi = nnz;
  while (lo2 < hi){ int m = (lo2+hi)>>1; if (row[m] < v+1) lo2 = m+1; else hi = m; }
  int e1 = lo2;
  float s = 0.f;
  #pragma unroll
  for (int i=0;i<7;i++){
    int e = e0 + i;
    int c  = (e < e1) ? colx[e] : 0;
    float wv = (e < e1) ? vals[e] : 0.f;
    col7[v*7+i] = c; val7[v*7+i] = wv; s += wv;
  }
  dvec[v] = s;
}

// ---- fused: s = spmm(x) over C=3, then h1 = relu(s@W1^T + d[v]*b1), bf16 out ----
__global__ void spmm_lin1_k(const float* __restrict__ x, const int* __restrict__ col7,
    const float* __restrict__ val7, const float* __restrict__ d,
    const float* __restrict__ W1, const float* __restrict__ b1,
    unsigned short* __restrict__ out, int V, int R){
  __shared__ float sW[192];
  __shared__ float sB[64];
  int tid = threadIdx.x;
  if (tid < 192) sW[tid] = W1[tid];
  if (tid < 64)  sB[tid] = b1[tid];
  __syncthreads();
  int r = blockIdx.x*256 + tid;
  if (r >= R) return;
  int b = r / V; int v = r - b*V;
  const float* xb = x + (size_t)b*V*3;
  int   cs[7]; float ws[7];
  #pragma unroll
  for (int i=0;i<7;i++){ cs[i] = col7[v*7+i]; ws[i] = val7[v*7+i]; }
  float s0=0.f, s1=0.f, s2=0.f;
  #pragma unroll
  for (int i=0;i<7;i++){
    const float* xr = xb + (size_t)cs[i]*3;
    s0 += ws[i]*xr[0]; s1 += ws[i]*xr[1]; s2 += ws[i]*xr[2];
  }
  float dv = d[v];
  unsigned short* orow = out + (size_t)r*64;
  #pragma unroll
  for (int cg=0; cg<8; ++cg){
    ushort8 o;
    #pragma unroll
    for (int k=0;k<8;k++){
      int c = cg*8 + k;
      float acc = dv*sB[c] + s0*sW[c*3] + s1*sW[c*3+1] + s2*sW[c*3+2];
      o[k] = f2bf(fmaxf(acc, 0.f));
    }
    *reinterpret_cast<ushort8*>(orow + cg*8) = o;
  }
}

// ---- layer-2: B-frag = spmm gather (deg-7) of h1; out = relu(B@W^T + d*b), bf16 ----
__global__ __launch_bounds__(256) void lin2_spmm_k(const unsigned short* __restrict__ in,
    const float* __restrict__ W, const float* __restrict__ bias,
    const int* __restrict__ col7, const float* __restrict__ val7,
    const float* __restrict__ dvec, unsigned short* __restrict__ out, int R, int V){
  constexpr int K = 64, N = 64, KP = K + 8, NF = N/16, KS = 2;
  __shared__ unsigned short sW[N * KP];
  __shared__ float sB[N];
  int tid = threadIdx.x;
  for (int i = tid*4; i < N*K; i += 1024){
    const float4 wv = *reinterpret_cast<const float4*>(W + i);
    int n = i / K, k = i - n*K;
    unsigned short* dst = &sW[n*KP + k];
    dst[0] = f2bf(wv.x); dst[1] = f2bf(wv.y); dst[2] = f2bf(wv.z); dst[3] = f2bf(wv.w);
  }
  if (tid < N) sB[tid] = bias[tid];
  __syncthreads();

  const int wave = tid >> 6, lane = tid & 63;
  const int l15 = lane & 15, lg = lane >> 4;
  const int rbase = blockIdx.x*128 + wave*32;

  int r0c = min(rbase + l15,      R-1);
  int r1c = min(rbase + 16 + l15, R-1);
  int b0i = r0c / V, v0 = r0c - b0i*V;
  int b1i = r1c / V, v1 = r1c - b1i*V;
  const unsigned short* base0 = in + (size_t)b0i*V*K + lg*8;
  const unsigned short* base1 = in + (size_t)b1i*V*K + lg*8;
  const unsigned short* aBase = &sW[l15*KP + lg*8];

  int  c0[7], c1[7]; float w0[7], w1[7];
  #pragma unroll
  for (int i=0;i<7;i++){ c0[i]=col7[v0*7+i]; w0[i]=val7[v0*7+i];
                         c1[i]=col7[v1*7+i]; w1[i]=val7[v1*7+i]; }

  f32x4 acc[NF][2];
  #pragma unroll
  for (int nf=0; nf<NF; ++nf){ acc[nf][0] = (f32x4)0.f; acc[nf][1] = (f32x4)0.f; }

  #pragma unroll
  for (int ks=0; ks<KS; ++ks){
    float a0[8], a1[8];
    #pragma unroll
    for (int k=0;k<8;k++){ a0[k]=0.f; a1[k]=0.f; }
    #pragma unroll
    for (int i=0;i<7;i++){
      ushort8 g0 = *reinterpret_cast<const ushort8*>(base0 + (size_t)c0[i]*K + ks*32);
      ushort8 g1 = *reinterpret_cast<const ushort8*>(base1 + (size_t)c1[i]*K + ks*32);
      #pragma unroll
      for (int k=0;k<8;k++){ a0[k] += w0[i]*bf2f(g0[k]); a1[k] += w1[i]*bf2f(g1[k]); }
    }
    short8v b0, b1;
    #pragma unroll
    for (int k=0;k<8;k++){ b0[k]=(short)f2bf(a0[k]); b1[k]=(short)f2bf(a1[k]); }
    #pragma unroll
    for (int nf=0; nf<NF; ++nf){
      short8v a = *reinterpret_cast<const short8v*>(aBase + nf*16*KP + ks*32);
      acc[nf][0] = __builtin_amdgcn_mfma_f32_16x16x32_bf16(a, b0, acc[nf][0], 0,0,0);
      acc[nf][1] = __builtin_amdgcn_mfma_f32_16x16x32_bf16(a, b1, acc[nf][1], 0,0,0);
    }
  }

  float d0 = dvec[v0], d1 = dvec[v1];
  #pragma unroll
  for (int rr=0; rr<2; ++rr){
    int r = rbase + rr*16 + l15;
    if (r >= R) continue;
    float ds = rr ? d1 : d0;
    #pragma unroll
    for (int nf=0; nf<NF; ++nf){
      int nb = nf*16 + lg*4;
      ushort4v o;
      #pragma unroll
      for (int reg=0; reg<4; ++reg){
        float v = fmaxf(acc[nf][rr][reg] + ds*sB[nb + reg], 0.f);
        o[reg] = f2bf(v);
      }
      *reinterpret_cast<ushort4v*>(out + (size_t)r*N + nb) = o;
    }
  }
}

// ---- layer-3: B-frag = spmm gather of h2p; relu + mean-pool into g (no h3 store) ----
__global__ __launch_bounds__(256) void lin3_spmm_mean_k(const unsigned short* __restrict__ in,
    const float* __restrict__ W, const float* __restrict__ bias,
    const int* __restrict__ col7, const float* __restrict__ val7,
    const float* __restrict__ dvec, float* __restrict__ g, int R, int V, int Bn){
  constexpr int K = 64, N = 128, KP = K + 8, NF = N/16, KS = 2;
  __shared__ unsigned short sW[N * KP];
  __shared__ float sB[N];
  __shared__ float gPart[2][128];
  int tid = threadIdx.x;
  for (int i = tid*4; i < N*K; i += 1024){
    const float4 wv = *reinterpret_cast<const float4*>(W + i);
    int n = i / K, k = i - n*K;
    unsigned short* dst = &sW[n*KP + k];
    dst[0] = f2bf(wv.x); dst[1] = f2bf(wv.y); dst[2] = f2bf(wv.z); dst[3] = f2bf(wv.w);
  }
  if (tid < N) sB[tid] = bias[tid];
  if (tid < 128){ gPart[0][tid] = 0.f; gPart[1][tid] = 0.f; }
  __syncthreads();

  const int wave = tid >> 6, lane = tid & 63;
  const int l15 = lane & 15, lg = lane >> 4;
  const int rbase = blockIdx.x*128 + wave*32;

  int r0 = rbase + l15;
  int r1 = rbase + 16 + l15;
  int r0c = min(r0, R-1), r1c = min(r1, R-1);
  int b0i = r0c / V, v0 = r0c - b0i*V;
  int b1i = r1c / V, v1 = r1c - b1i*V;
  const unsigned short* base0 = in + (size_t)b0i*V*K + lg*8;
  const unsigned short* base1 = in + (size_t)b1i*V*K + lg*8;
  const unsigned short* aBase = &sW[l15*KP + lg*8];

  int  c0[7], c1[7]; float w0[7], w1[7];
  #pragma unroll
  for (int i=0;i<7;i++){ c0[i]=col7[v0*7+i]; w0[i]=val7[v0*7+i];
                         c1[i]=col7[v1*7+i]; w1[i]=val7[v1*7+i]; }

  f32x4 acc[NF][2];
  #pragma unroll
  for (int nf=0; nf<NF; ++nf){ acc[nf][0] = (f32x4)0.f; acc[nf][1] = (f32x4)0.f; }

  #pragma unroll
  for (int ks=0; ks<KS; ++ks){
    float a0[8], a1[8];
    #pragma unroll
    for (int k=0;k<8;k++){ a0[k]=0.f; a1[k]=0.f; }
    #pragma unroll
    for (int i=0;i<7;i++){
      ushort8 g0 = *reinterpret_cast<const ushort8*>(base0 + (size_t)c0[i]*K + ks*32);
      ushort8 g1 = *reinterpret_cast<const ushort8*>(base1 + (size_t)c1[i]*K + ks*32);
      #pragma unroll
      for (int k=0;k<8;k++){ a0[k] += w0[i]*bf2f(g0[k]); a1[k] += w1[i]*bf2f(g1[k]); }
    }
    short8v b0, b1;
    #pragma unroll
    for (int k=0;k<8;k++){ b0[k]=(short)f2bf(a0[k]); b1[k]=(short)f2bf(a1[k]); }
    #pragma unroll
    for (int nf=0; nf<NF; ++nf){
      short8v a = *reinterpret_cast<const short8v*>(aBase + nf*16*KP + ks*32);
      acc[nf][0] = __builtin_amdgcn_mfma_f32_16x16x32_bf16(a, b0, acc[nf][0], 0,0,0);
      acc[nf][1] = __builtin_amdgcn_mfma_f32_16x16x32_bf16(a, b1, acc[nf][1], 0,0,0);
    }
  }

  const int b0blk = (blockIdx.x*128) / V;
  bool ok0 = r0 < R, ok1 = r1 < R;
  float d0 = dvec[v0], d1 = dvec[v1];
  bool in00 = ok0 && (b0i == b0blk), in01 = ok0 && (b0i == b0blk+1);
  bool in10 = ok1 && (b1i == b0blk), in11 = ok1 && (b1i == b0blk+1);

  #pragma unroll
  for (int nf=0; nf<NF; ++nf){
    #pragma unroll
    for (int reg=0; reg<4; ++reg){
      int c = nf*16 + lg*4 + reg;
      float v0f = fmaxf(acc[nf][0][reg] + d0*sB[c], 0.f);
      float v1f = fmaxf(acc[nf][1][reg] + d1*sB[c], 0.f);
      float sA = (in00 ? v0f : 0.f) + (in10 ? v1f : 0.f);
      float sBv= (in01 ? v0f : 0.f) + (in11 ? v1f : 0.f);
      #pragma unroll
      for (int m=1; m<16; m<<=1){
        sA  += __shfl_xor(sA,  m);
        sBv += __shfl_xor(sBv, m);
      }
      if (l15 == 0){
        atomicAdd(&gPart[0][c], sA);
        atomicAdd(&gPart[1][c], sBv);
      }
    }
  }
  __syncthreads();
  if (tid < 128){
    float a = gPart[0][tid];
    if (a != 0.f) atomicAdd(&g[b0blk*128 + tid], a);
    float b2 = gPart[1][tid];
    if (b2 != 0.f && b0blk+1 < Bn) atomicAdd(&g[(b0blk+1)*128 + tid], b2);
  }
}

// ---- fused VAE head: one block per batch element ----
__global__ __launch_bounds__(256) void head2_k(const float* __restrict__ g,
    const float* __restrict__ Wfc, const float* __restrict__ bfc,
    const float* __restrict__ Wmu, const float* __restrict__ bmu,
    const float* __restrict__ Wlv, const float* __restrict__ blv,
    const float* __restrict__ eps, const float* __restrict__ Wd1,
    const float* __restrict__ bd1, float* __restrict__ mu_out,
    float* __restrict__ lv_out, float* __restrict__ zp, float invV){
  int b = blockIdx.x;
  int tid = threadIdx.x;
  __shared__ float sG[128];
  __shared__ float sF[256];
  __shared__ float sMu[32];
  __shared__ float sLv[32];
  __shared__ float sZ[32];
  if (tid < 128) sG[tid] = g[b*128 + tid] * invV;
  __syncthreads();
  {
    const float4* wr = reinterpret_cast<const float4*>(Wfc + tid*128);
    float acc = bfc[tid];
    #pragma unroll 8
    for (int k4=0;k4<32;k4++){
      float4 wv = wr[k4];
      acc += sG[k4*4]*wv.x + sG[k4*4+1]*wv.y + sG[k4*4+2]*wv.z + sG[k4*4+3]*wv.w;
    }
    sF[tid] = fmaxf(acc, 0.f);
  }
  __syncthreads();
  if (tid < 64){
    int c = tid & 31;
    bool isMu = tid < 32;
    const float4* wr = reinterpret_cast<const float4*>((isMu ? Wmu : Wlv) + c*256);
    float acc = isMu ? bmu[c] : blv[c];
    #pragma unroll 8
    for (int k4=0;k4<64;k4++){
      float4 wv = wr[k4];
      acc += sF[k4*4]*wv.x + sF[k4*4+1]*wv.y + sF[k4*4+2]*wv.z + sF[k4*4+3]*wv.w;
    }
    if (isMu){ sMu[c] = acc; mu_out[b*32+c] = acc; }
    else {
      acc = fminf(20.f, fmaxf(-20.f, acc));
      sLv[c] = acc; lv_out[b*32+c] = acc;
    }
  }
  __syncthreads();
  if (tid < 32) sZ[tid] = sMu[tid] + eps[b*32+tid]*expf(0.5f*sLv[tid]);
  __syncthreads();
  if (tid < 128){
    const float* wr = Wd1 + tid*35;
    float acc = bd1[tid];
    #pragma unroll
    for (int k=0;k<32;k++) acc += sZ[k]*wr[k];
    zp[b*128 + tid] = acc;
  }
}

// ---- decoder layer 2, B built on the fly: hd1[c]=relu(zp[b][c]+tmpl[v]·Wd1[c,32:35]) ----
__global__ __launch_bounds__(256) void lin_dec2z_k(const float* __restrict__ zp,
    const float* __restrict__ tmpl, const float* __restrict__ Wd1,
    const float* __restrict__ W, const float* __restrict__ bias,
    unsigned short* __restrict__ out, int R, int V, int Bn){
  constexpr int K = 128, N = 128, KP = K + 8, NF = N/16, KS = 4;
  __shared__ unsigned short sW[N * KP];
  __shared__ float sB[N];
  __shared__ float sZP[16*128];
  __shared__ float sWT[128*3];
  int tid = threadIdx.x;
  for (int i = tid*4; i < N*K; i += 1024){
    const float4 wv = *reinterpret_cast<const float4*>(W + i);
    int n = i / K, k = i - n*K;
    unsigned short* dst = &sW[n*KP + k];
    dst[0] = f2bf(wv.x); dst[1] = f2bf(wv.y); dst[2] = f2bf(wv.z); dst[3] = f2bf(wv.w);
  }
  if (tid < N) sB[tid] = bias[tid];
  for (int i = tid; i < Bn*128; i += 256) sZP[i] = zp[i];
  if (tid < 128){
    sWT[tid*3+0] = Wd1[tid*35+32];
    sWT[tid*3+1] = Wd1[tid*35+33];
    sWT[tid*3+2] = Wd1[tid*35+34];
  }
  __syncthreads();

  const int wave = tid >> 6, lane = tid & 63;
  const int l15 = lane & 15, lg = lane >> 4;
  const int rbase = blockIdx.x*128 + wave*32;

  int r0c = min(rbase + l15,      R-1);
  int r1c = min(rbase + 16 + l15, R-1);
  int b0i = r0c / V, v0 = r0c - b0i*V;
  int b1i = r1c / V, v1 = r1c - b1i*V;
  float t0x = tmpl[v0*3], t0y = tmpl[v0*3+1], t0z = tmpl[v0*3+2];
  float t1x = tmpl[v1*3], t1y = tmpl[v1*3+1], t1z = tmpl[v1*3+2];
  const float* zp0 = sZP + b0i*128;
  const float* zp1 = sZP + b1i*128;
  const unsigned short* aBase = &sW[l15*KP + lg*8];

  f32x4 acc[NF][2];
  #pragma unroll
  for (int nf=0; nf<NF; ++nf){ acc[nf][0] = (f32x4)0.f; acc[nf][1] = (f32x4)0.f; }

  #pragma unroll
  for (int ks=0; ks<KS; ++ks){
    short8v b0, b1;
    #pragma unroll
    for (int k=0;k<8;k++){
      int c = lg*8 + ks*32 + k;
      const float* wt = sWT + c*3;
      float h0 = zp0[c] + t0x*wt[0] + t0y*wt[1] + t0z*wt[2];
      float h1 = zp1[c] + t1x*wt[0] + t1y*wt[1] + t1z*wt[2];
      b0[k] = (short)f2bf(fmaxf(h0, 0.f));
      b1[k] = (short)f2bf(fmaxf(h1, 0.f));
    }
    #pragma unroll
    for (int nf=0; nf<NF; ++nf){
      short8v a = *reinterpret_cast<const short8v*>(aBase + nf*16*KP + ks*32);
      acc[nf][0] = __builtin_amdgcn_mfma_f32_16x16x32_bf16(a, b0, acc[nf][0], 0,0,0);
      acc[nf][1] = __builtin_amdgcn_mfma_f32_16x16x32_bf16(a, b1, acc[nf][1], 0,0,0);
    }
  }

  #pragma unroll
  for (int rr=0; rr<2; ++rr){
    int r = rbase + rr*16 + l15;
    if (r >= R) continue;
    #pragma unroll
    for (int nf=0; nf<NF; ++nf){
      int nb = nf*16 + lg*4;
      ushort4v o;
      #pragma unroll
      for (int reg=0; reg<4; ++reg){
        float v = fmaxf(acc[nf][rr][reg] + sB[nb + reg], 0.f);
        o[reg] = f2bf(v);
      }
      *reinterpret_cast<ushort4v*>(out + (size_t)r*N + nb) = o;
    }
  }
}

// ---- decoder layers 3+4 fused: h4 = relu(in@Wd3^T+bd3); recon = tmpl + h4@Wd4^T+bd4 ----
__global__ __launch_bounds__(256) void lin_dec34_k(const unsigned short* __restrict__ in,
    const float* __restrict__ W3, const float* __restrict__ b3,
    const float* __restrict__ W4, const float* __restrict__ b4,
    const float* __restrict__ tmpl, float* __restrict__ out, int R, int V){
  constexpr int K = 128, N = 64, KP = K + 8, NF = N/16, KS = K/32;
  __shared__ unsigned short sW[N * KP];
  __shared__ float sB3[N];
  __shared__ float sW4[3*64];
  int tid = threadIdx.x;
  for (int i = tid*4; i < N*K; i += 1024){
    const float4 wv = *reinterpret_cast<const float4*>(W3 + i);
    int n = i / K, k = i - n*K;
    unsigned short* dst = &sW[n*KP + k];
    dst[0] = f2bf(wv.x); dst[1] = f2bf(wv.y); dst[2] = f2bf(wv.z); dst[3] = f2bf(wv.w);
  }
  if (tid < N) sB3[tid] = b3[tid];
  if (tid < 192) sW4[tid] = W4[tid];
  __syncthreads();

  const int wave = tid >> 6, lane = tid & 63;
  const int l15 = lane & 15, lg = lane >> 4;
  const int rbase = blockIdx.x*128 + wave*32;

  int r0c = min(rbase + l15,      R-1);
  int r1c = min(rbase + 16 + l15, R-1);
  const unsigned short* bp0 = in + (size_t)r0c*K + lg*8;
  const unsigned short* bp1 = in + (size_t)r1c*K + lg*8;
  const unsigned short* aBase = &sW[l15*KP + lg*8];

  f32x4 acc[NF][2];
  #pragma unroll
  for (int nf=0; nf<NF; ++nf){ acc[nf][0] = (f32x4)0.f; acc[nf][1] = (f32x4)0.f; }

  #pragma unroll
  for (int ks=0; ks<KS; ++ks){
    short8v b0 = *reinterpret_cast<const short8v*>(bp0 + ks*32);
    short8v b1 = *reinterpret_cast<const short8v*>(bp1 + ks*32);
    #pragma unroll
    for (int nf=0; nf<NF; ++nf){
      short8v a = *reinterpret_cast<const short8v*>(aBase + nf*16*KP + ks*32);
      acc[nf][0] = __builtin_amdgcn_mfma_f32_16x16x32_bf16(a, b0, acc[nf][0], 0,0,0);
      acc[nf][1] = __builtin_amdgcn_mfma_f32_16x16x32_bf16(a, b1, acc[nf][1], 0,0,0);
    }
  }

  #pragma unroll
  for (int rr=0; rr<2; ++rr){
    int r = rbase + rr*16 + l15;
    float p0 = 0.f, p1 = 0.f, p2 = 0.f;
    #pragma unroll
    for (int nf=0; nf<NF; ++nf){
      #pragma unroll
      for (int reg=0; reg<4; ++reg){
        int c = nf*16 + lg*4 + reg;
        float h = fmaxf(acc[nf][rr][reg] + sB3[c], 0.f);
        p0 += h*sW4[c]; p1 += h*sW4[64+c]; p2 += h*sW4[128+c];
      }
    }
    p0 += __shfl_xor(p0,16); p0 += __shfl_xor(p0,32);
    p1 += __shfl_xor(p1,16); p1 += __shfl_xor(p1,32);
    p2 += __shfl_xor(p2,16); p2 += __shfl_xor(p2,32);
    if (lg == 0 && r < R){
      int v = r % V;
      out[(size_t)r*3+0] = tmpl[v*3+0] + p0 + b4[0];
      out[(size_t)r*3+1] = tmpl[v*3+1] + p1 + b4[1];
      out[(size_t)r*3+2] = tmpl[v*3+2] + p2 + b4[2];
    }
  }
}

extern "C" void kernel_launch(void* const* d_in, const int* in_sizes, int n_in,
                              void* d_out, int out_size, void* d_ws, size_t ws_size,
                              hipStream_t stream){
  const float* x    = (const float*)d_in[0];
  const float* eps  = (const float*)d_in[1];
  const int*   row  = (const int*)d_in[2];
  const int*   colx = (const int*)d_in[3];
  const float* vals = (const float*)d_in[4];
  const float* tmpl = (const float*)d_in[5];
  const float* W1 = (const float*)d_in[6];  const float* b1 = (const float*)d_in[7];
  const float* W2 = (const float*)d_in[8];  const float* b2 = (const float*)d_in[9];
  const float* W3 = (const float*)d_in[10]; const float* b3 = (const float*)d_in[11];
  const float* Wfc= (const float*)d_in[12]; const float* bfc= (const float*)d_in[13];
  const float* Wmu= (const float*)d_in[14]; const float* bmu= (const float*)d_in[15];
  const float* Wlv= (const float*)d_in[16]; const float* blv= (const float*)d_in[17];
  const float* Wd1= (const float*)d_in[18]; const float* bd1= (const float*)d_in[19];
  const float* Wd2= (const float*)d_in[20]; const float* bd2= (const float*)d_in[21];
  const float* Wd3= (const float*)d_in[22]; const float* bd3= (const float*)d_in[23];
  const float* Wd4= (const float*)d_in[24]; const float* bd4= (const float*)d_in[25];

  int V   = in_sizes[5] / 3;     // 10242
  int Bn  = in_sizes[1] / 32;    // 16
  int nnz = in_sizes[2];         // 71682
  int R   = Bn * V;              // 163872

  // workspace layout
  char* w = (char*)d_ws;
  size_t off = 0;
  auto alloc = [&](size_t bytes)->char*{
    char* p = w + off; off = (off + bytes + 255) & ~(size_t)255; return p;
  };
  unsigned short* bufA = (unsigned short*)alloc((size_t)R * 128 * 2); // h1 (64ch) then hd2 (128ch)
  unsigned short* bufB = (unsigned short*)alloc((size_t)R * 64  * 2); // h2p (64ch)
  int*   col7 = (int*)alloc((size_t)V*7*4);
  float* val7 = (float*)alloc((size_t)V*7*4);
  float* dvec = (float*)alloc((size_t)V*4);
  float* g    = (float*)alloc((size_t)Bn*128*4);
  float* zp   = (float*)alloc((size_t)Bn*128*4);

  float* recon  = (float*)d_out;
  float* mu_out = recon + (size_t)R*3;
  float* lv_out = mu_out + (size_t)Bn*32;

  int mfmaGrid = (R + 127) / 128;

  // prep (col7/val7/dvec + zero g)
  prep_k<<<(V+255)/256, 256, 0, stream>>>(row, colx, vals, nnz, col7, val7, dvec, g, V, Bn*128);

  // encoder: h1 = relu(spmm(x)@W1^T + d*b1); h2p = relu(spmm(h1)@W2^T + d*b2); g = mean relu(spmm(h2p)@W3^T + d*b3)
  spmm_lin1_k<<<(R+255)/256, 256, 0, stream>>>(x, col7, val7, dvec, W1, b1, bufA, V, R);
  lin2_spmm_k<<<mfmaGrid, 256, 0, stream>>>(bufA, W2, b2, col7, val7, dvec, bufB, R, V);
  lin3_spmm_mean_k<<<mfmaGrid, 256, 0, stream>>>(bufB, W3, b3, col7, val7, dvec, g, R, V, Bn);

  // head (feat/mu/lv/z/zpart)
  head2_k<<<Bn, 256, 0, stream>>>(g, Wfc, bfc, Wmu, bmu, Wlv, blv, eps, Wd1, bd1,
                                  mu_out, lv_out, zp, 1.0f/(float)V);

  // decoder
  lin_dec2z_k<<<mfmaGrid, 256, 0, stream>>>(zp, tmpl, Wd1, Wd2, bd2, bufA, R, V, Bn);
  lin_dec34_k<<<mfmaGrid, 256, 0, stream>>>(bufA, Wd3, bd3, Wd4, bd4, tmpl, recon, R, V);
}